// Round 10
// baseline (282.094 us; speedup 1.0000x reference)
//
#include <hip/hip_runtime.h>
#include <math.h>

// Problem constants
#define B_ 2
#define S_ 2048
#define D_ 1024
#define H_ 16
#define HKV_ 4
#define HD_ 64
#define SD_ 16

typedef __attribute__((ext_vector_type(8))) short bf16x8;
typedef __attribute__((ext_vector_type(4))) short bf16x4;
typedef __attribute__((ext_vector_type(4))) float f32x4;
typedef __attribute__((ext_vector_type(8))) unsigned short us8;
typedef __attribute__((ext_vector_type(4))) unsigned short us4;

#define LOG2E 1.4426950408889634f

__device__ __forceinline__ unsigned short f2bf(float f) {
  unsigned int u = __builtin_bit_cast(unsigned int, f);
  u += 0x7fffu + ((u >> 16) & 1u);   // RNE; inputs are finite
  return (unsigned short)(u >> 16);
}

// global -> LDS async DMA, 16B per lane; LDS dest wave-uniform base + lane*16.
__device__ __forceinline__ void gload16(const unsigned short* g, unsigned short* l) {
  __builtin_amdgcn_global_load_lds(
      (const __attribute__((address_space(1))) unsigned int*)g,
      (__attribute__((address_space(3))) unsigned int*)l, 16, 0, 0);
}

// ---------------------------------------------------------------------------
// Kernel 0: fp32 -> bf16 convert for GEMM operands.
// ---------------------------------------------------------------------------
__global__ __launch_bounds__(256) void convert_bf16(
    const float* __restrict__ x, const float* __restrict__ wq,
    const float* __restrict__ wk, const float* __restrict__ wv,
    const float* __restrict__ wo, unsigned short* __restrict__ xb,
    unsigned short* __restrict__ wqkv, unsigned short* __restrict__ wob) {
  const int blk = blockIdx.x;
  const float* src;
  unsigned short* dst;
  int off;
  if (blk < 2048)      { src = x;  dst = xb;             off = blk * 2048; }
  else if (blk < 2560) { src = wq; dst = wqkv;           off = (blk - 2048) * 2048; }
  else if (blk < 2688) { src = wk; dst = wqkv + 1048576; off = (blk - 2560) * 2048; }
  else if (blk < 2816) { src = wv; dst = wqkv + 1310720; off = (blk - 2688) * 2048; }
  else                 { src = wo; dst = wob;            off = (blk - 2816) * 2048; }
  const int i = off + threadIdx.x * 8;
  float4 a = *(const float4*)(src + i);
  float4 b = *(const float4*)(src + i + 4);
  us8 o;
  o[0] = f2bf(a.x); o[1] = f2bf(a.y); o[2] = f2bf(a.z); o[3] = f2bf(a.w);
  o[4] = f2bf(b.x); o[5] = f2bf(b.y); o[6] = f2bf(b.z); o[7] = f2bf(b.w);
  *(us8*)(dst + i) = o;
}

// ---------------------------------------------------------------------------
// Kernel A/D: bf16 MFMA GEMM, m97 staging, 64x128 tile.
// ---------------------------------------------------------------------------
__global__ __launch_bounds__(256) void gemm_bf16(
    const unsigned short* __restrict__ A, const unsigned short* __restrict__ Bm,
    const float* __restrict__ bias, float* __restrict__ C, int N) {
  __shared__ unsigned short As[64 * 64];
  __shared__ unsigned short Bs[128 * 64];
  const int tid = threadIdx.x;
  const int w = tid >> 6, lane = tid & 63;
  const int nm = lane & 15, quad = lane >> 4;
  const int m0 = blockIdx.y * 64, n0 = blockIdx.x * 128;
  const int wn = w * 32;

  f32x4 acc[4][2] = {};
  int arow[2], acol[2], brow[4], bcol[4];
#pragma unroll
  for (int it = 0; it < 2; ++it) {
    int s = it * 256 + tid;
    arow[it] = s >> 3;
    acol[it] = ((s & 7) ^ (arow[it] & 7)) * 8;
  }
#pragma unroll
  for (int it = 0; it < 4; ++it) {
    int s = it * 256 + tid;
    brow[it] = s >> 3;
    bcol[it] = ((s & 7) ^ (brow[it] & 7)) * 8;
  }

  for (int k0 = 0; k0 < 1024; k0 += 64) {
    __syncthreads();
#pragma unroll
    for (int it = 0; it < 2; ++it)
      gload16(A + (size_t)(m0 + arow[it]) * 1024 + k0 + acol[it],
              &As[(it * 256 + w * 64) * 8]);
#pragma unroll
    for (int it = 0; it < 4; ++it)
      gload16(Bm + (size_t)(n0 + brow[it]) * 1024 + k0 + bcol[it],
              &Bs[(it * 256 + w * 64) * 8]);
    __syncthreads();

#pragma unroll
    for (int ks = 0; ks < 2; ++ks) {
      const int cq = ks * 4 + quad;
      bf16x8 af[4], bfr[2];
#pragma unroll
      for (int mi = 0; mi < 4; ++mi) {
        const int m = mi * 16 + nm;
        af[mi] = *(const bf16x8*)&As[(m * 8 + (cq ^ (m & 7))) * 8];
      }
#pragma unroll
      for (int ni = 0; ni < 2; ++ni) {
        const int n = wn + ni * 16 + nm;
        bfr[ni] = *(const bf16x8*)&Bs[(n * 8 + (cq ^ (n & 7))) * 8];
      }
#pragma unroll
      for (int mi = 0; mi < 4; ++mi)
#pragma unroll
        for (int ni = 0; ni < 2; ++ni)
          acc[mi][ni] = __builtin_amdgcn_mfma_f32_16x16x32_bf16(
              af[mi], bfr[ni], acc[mi][ni], 0, 0, 0);
    }
  }

  float bv[2] = {0.f, 0.f};
  if (bias) {
#pragma unroll
    for (int ni = 0; ni < 2; ++ni) bv[ni] = bias[n0 + wn + ni * 16 + nm];
  }
#pragma unroll
  for (int mi = 0; mi < 4; ++mi) {
#pragma unroll
    for (int r = 0; r < 4; ++r) {
      const int row = m0 + mi * 16 + quad * 4 + r;
      float* crow = C + (size_t)row * N + n0 + wn + nm;
#pragma unroll
      for (int ni = 0; ni < 2; ++ni) crow[ni * 16] = acc[mi][ni][r] + bv[ni];
    }
  }
}

// ---------------------------------------------------------------------------
// Kernel B: RoPE + scatter (bf16) + low-rank sparsity proj (slots 0..19).
// q scaled by log2e/8, qsp by log2e/4 so attn uses native exp2.
// ---------------------------------------------------------------------------
__global__ __launch_bounds__(256) void rope_scatter(
    const float* __restrict__ P, const float* __restrict__ Ws,
    const float* __restrict__ bs, unsigned short* __restrict__ qh,
    unsigned short* __restrict__ kh, unsigned short* __restrict__ qsp,
    unsigned short* __restrict__ ksp) {
  __shared__ float wsl[16 * 64];
  __shared__ float bsl[16];
  __shared__ float rbuf[4][64];
  const int tid = threadIdx.x;
  const int row = blockIdx.x;
  const int b = row >> 11;
  const int s = row & 2047;
  {
    *(float4*)&wsl[tid * 4] = *(const float4*)&Ws[tid * 4];
    if (tid < 16) bsl[tid] = bs[tid];
  }
  __syncthreads();
  const int w = tid >> 6, lane = tid & 63;
  const int i = lane & 31, halfu = lane >> 5;
  const float theta = powf(10000.f, -((float)(2 * i) * (1.f / 64.f)));
  const float f = (float)s * theta;
  const float cf = cosf(f);
  const float sf = sinf(f);
  for (int slot = w; slot < 20; slot += 4) {
    float val = P[(size_t)row * 1536 + slot * 64 + lane];
    float partner = __shfl_xor(val, 32);
    float rot = halfu ? partner : -partner;
    float r = val * cf + rot * sf;
    unsigned short* dst;
    unsigned short* spdst;
    float qscale, spscale;
    if (slot < 16) {
      dst = qh + ((size_t)(b * 16 + slot) * 2048 + s) * 64;
      spdst = qsp + ((size_t)(b * 16 + slot) * 2048 + s) * 16;
      qscale = 0.125f * LOG2E; spscale = 0.25f * LOG2E;
    } else {
      int hh = slot - 16;
      dst = kh + ((size_t)(b * 4 + hh) * 2048 + s) * 64;
      spdst = ksp + ((size_t)(b * 4 + hh) * 2048 + s) * 16;
      qscale = 1.f; spscale = 1.f;
    }
    dst[lane] = f2bf(r * qscale);
    rbuf[w][lane] = r;
    int p = lane >> 4, j = lane & 15;
    float partial = 0.f;
#pragma unroll
    for (int t = 0; t < 16; ++t)
      partial += wsl[j * 64 + p * 16 + t] * rbuf[w][p * 16 + t];
    partial += __shfl_xor(partial, 16);
    partial += __shfl_xor(partial, 32);
    if (p == 0) spdst[j] = f2bf((partial + bsl[j]) * spscale);
  }
}

// ---------------------------------------------------------------------------
// Kernel B2: one-time V transpose: proj v-cols (f32) -> vt[bkv][d=64][s=2048] bf16.
// ---------------------------------------------------------------------------
__global__ __launch_bounds__(256) void v_transpose(
    const float* __restrict__ proj, unsigned short* __restrict__ vt) {
  __shared__ unsigned short t_[64 * 72];
  const int bkv = blockIdx.y;
  const int s0 = blockIdx.x * 64;
  const int b = bkv >> 2, hkv = bkv & 3;
  const int tid = threadIdx.x;
  const int sl = tid >> 2;
  const int c0 = (tid & 3) * 16;
  const float* src = proj + ((size_t)b * 2048 + s0 + sl) * 1536 + 1280 + hkv * 64 + c0;
  us8 o0, o1;
#pragma unroll
  for (int t = 0; t < 8; ++t) { o0[t] = f2bf(src[t]); o1[t] = f2bf(src[8 + t]); }
  *(us8*)&t_[sl * 72 + c0] = o0;
  *(us8*)&t_[sl * 72 + c0 + 8] = o1;
  __syncthreads();
  const int d = tid >> 2;
  const int sc_ = (tid & 3) * 16;
  us8 w0, w1;
#pragma unroll
  for (int t = 0; t < 8; ++t) w0[t] = t_[(sc_ + t) * 72 + d];
#pragma unroll
  for (int t = 0; t < 8; ++t) w1[t] = t_[(sc_ + 8 + t) * 72 + d];
  unsigned short* dst = vt + (size_t)bkv * 131072 + (size_t)d * 2048 + s0 + sc_;
  *(us8*)dst = w0;
  *(us8*)(dst + 8) = w1;
}

// ---------------------------------------------------------------------------
// Kernel C: gated causal flash attention.
// R21: revert R20's counted-vmcnt graft (58->86 regression; catalog T3/T4
// gate confirmed: counted vmcnt only pays inside a per-phase-interleaved
// schedule). Back to R19's proven per-tile __syncthreads double-buffer, and
// attack the verified constraint instead: VALUBusy ~50% at 4 waves/SIMD
// (trans-dominated score path, latency gaps unfilled; grid caps 2 blocks/CU).
// -> 1024-thread blocks, 16 waves: ws = w>>2 in 0..3 owns 16 keys, wr = w&3
// owns 16 q-rows. Key payoff: with 16 keys/wave, the swapped-QK^T output
// element (q=nm, key=quad*4+r) IS the A-fragment element (row=nm,
// k=quad*4+r) of mfma_f32_16x16x16bf16_1k -> P stays IN REGISTERS (pack 4
// scores to bf16x4, feed PV directly). Pt LDS eliminated; per-wave work
// halves; 2 blocks x 16 waves = 8 waves/SIMD. O combined 4-way at the two
// epilogues via atomicAdd on shared (ds_add_f32, disjoint addresses).
// __launch_bounds__(1024, 8) clamps VGPR <= 64.
// ---------------------------------------------------------------------------
template <bool MASK>
__device__ __forceinline__ void attn_tile(
    const unsigned short* __restrict__ Ksb, const unsigned short* __restrict__ Vsb,
    const unsigned short* __restrict__ Kspb_,
    bf16x8 qa0, bf16x8 qa1, bf16x8 qspa, int j0, int qrow0, int nm, int quad,
    int ws, float& l_q, f32x4 O[4]) {
  const int kg0 = j0 + ws * 16;          // this wave's 16-key group base
  if (MASK && (kg0 > qrow0 + 15)) return;  // fully masked: contributes nothing

  const int krow = ws * 16 + nm;
  const int r7 = krow & 7;
  bf16x8 kb0 = *(const bf16x8*)&Ksb[(krow * 8 + (quad ^ r7)) * 8];
  bf16x8 kb1 = *(const bf16x8*)&Ksb[(krow * 8 + ((4 + quad) ^ r7)) * 8];
  bf16x8 gb = *(const bf16x8*)&Kspb_[(krow * 2 + (quad & 1)) * 8];
  f32x4 z = {0.f, 0.f, 0.f, 0.f};
  // swapped operands: A = K (rows = keys), B = Q (cols = q = nm)
  f32x4 s = __builtin_amdgcn_mfma_f32_16x16x32_bf16(kb0, qa0, z, 0, 0, 0);
  s = __builtin_amdgcn_mfma_f32_16x16x32_bf16(kb1, qa1, s, 0, 0, 0);
  f32x4 g = __builtin_amdgcn_mfma_f32_16x16x32_bf16(gb, qspa, z, 0, 0, 0);
  const int qv = qrow0 + nm;
  f32x4 ps;
#pragma unroll
  for (int r = 0; r < 4; ++r) {
    // sigmoid via raw v_rcp + v_exp (g pre-scaled by log2e)
    float gate = __builtin_amdgcn_rcpf(1.f + __builtin_amdgcn_exp2f(-g[r]));
    float v = s[r] * gate;               // s pre-scaled by log2e
    if (MASK && (kg0 + 15 > qrow0)) {
      const int key = kg0 + quad * 4 + r;
      v = (key > qv) ? -INFINITY : v;
    }
    float p = __builtin_amdgcn_exp2f(v); // exp2(-inf) == 0
    l_q += p;
    ps[r] = p;
  }
  // in-register P: A-frag of 16x16x16 is (row=nm=q, k=quad*4+j=key offset)
  // = exactly the elements this lane just computed.
  bf16x4 pa;
  pa[0] = (short)f2bf(ps[0]); pa[1] = (short)f2bf(ps[1]);
  pa[2] = (short)f2bf(ps[2]); pa[3] = (short)f2bf(ps[3]);
  const int c = ws * 2 + (quad >> 1);    // key chunk in V^T row
#pragma unroll
  for (int dt = 0; dt < 4; ++dt) {
    const int vrow = dt * 16 + nm;
    bf16x4 vb = *(const bf16x4*)&Vsb[(vrow * 8 + (c ^ (vrow & 7))) * 8 + (quad & 1) * 4];
    O[dt] = __builtin_amdgcn_mfma_f32_16x16x16bf16_1k(pa, vb, O[dt], 0, 0, 0);
  }
}

__global__ __launch_bounds__(1024, 8) void attn_kernel(
    const unsigned short* __restrict__ qh, const unsigned short* __restrict__ kh,
    const unsigned short* __restrict__ vt, const unsigned short* __restrict__ qsp,
    const unsigned short* __restrict__ ksp, unsigned short* __restrict__ ao) {
  __shared__ unsigned short Ks[2][64 * 64];
  __shared__ unsigned short Vs[2][64 * 64];
  __shared__ unsigned short Ksp[2][64 * 16];
  __shared__ float Ox[4][16][64];   // [wr][dt*4+r][lane] O-combine
  __shared__ float Lxs[4][4][16];   // [wr][ws][q] l exchange

  const int tid = threadIdx.x;
  const int w = tid >> 6;       // 0..15
  const int ws = w >> 2;        // key quarter: 16 keys
  const int wr = w & 3;         // q-row group (16 rows)
  const int lane = tid & 63;
  const int nm = lane & 15;
  const int quad = lane >> 4;
  const int bh = blockIdx.y;
  const int b = bh >> 4, h = bh & 15;
  const int hkv = h >> 2;
  const size_t kbase = (size_t)(b * 4 + hkv) * 2048 * 64;
  const size_t vbase = (size_t)(b * 4 + hkv) * 131072;
  const size_t kspb = (size_t)(b * 4 + hkv) * 2048 * 16;

  // staging coords: waves 0-7 stage K (512 lanes x 16B), waves 8-15 stage V;
  // waves 0-1 additionally stage Ksp (128 lanes x 16B).
  const int Lc = tid & 511;
  const int sr = Lc >> 3;
  const int sc = ((Lc & 7) ^ (sr & 7)) * 8;

#define STAGE(BUF, J0)                                                         \
  {                                                                            \
    if (w < 8) {                                                               \
      gload16(kh + kbase + (size_t)((J0) + sr) * 64 + sc,                      \
              &Ks[BUF][(w * 64) * 8]);                                         \
      if (w < 2)                                                               \
        gload16(ksp + kspb + (size_t)((J0) + (tid >> 1)) * 16 + (tid & 1) * 8, \
                &Ksp[BUF][w * 512]);                                           \
    } else {                                                                   \
      gload16(vt + vbase + (size_t)sr * 2048 + (J0) + sc,                      \
              &Vs[BUF][((w - 8) * 64) * 8]);                                   \
    }                                                                          \
  }

  const int qxA = 31 - blockIdx.x;  // heavy tile
  const int qxB = blockIdx.x;       // light tile
  const int qrow0A = qxA * 64 + wr * 16;
  const int qrow0B = qxB * 64 + wr * 16;

  // q fragments (row group wr; all 4 ws quarters load the same Q - L2-hot)
  const size_t qbA = ((size_t)(b * 16 + h) * 2048 + qrow0A + nm) * 64;
  bf16x8 qa0A = *(const bf16x8*)(qh + qbA + quad * 8);
  bf16x8 qa1A = *(const bf16x8*)(qh + qbA + 32 + quad * 8);
  const size_t qbB = ((size_t)(b * 16 + h) * 2048 + qrow0B + nm) * 64;
  bf16x8 qa0B = *(const bf16x8*)(qh + qbB + quad * 8);
  bf16x8 qa1B = *(const bf16x8*)(qh + qbB + 32 + quad * 8);
  bf16x8 qspaA = {0, 0, 0, 0, 0, 0, 0, 0};
  bf16x8 qspaB = {0, 0, 0, 0, 0, 0, 0, 0};
  if (quad < 2) {
    qspaA = *(const bf16x8*)(qsp + ((size_t)(b * 16 + h) * 2048 + qrow0A + nm) * 16 + quad * 8);
    qspaB = *(const bf16x8*)(qsp + ((size_t)(b * 16 + h) * 2048 + qrow0B + nm) * 16 + quad * 8);
  }

  float l_q = 0.f;
  f32x4 O[4] = {{0.f, 0.f, 0.f, 0.f}, {0.f, 0.f, 0.f, 0.f},
                {0.f, 0.f, 0.f, 0.f}, {0.f, 0.f, 0.f, 0.f}};

  // ---------------- phase A (heavy q-tile) ----------------
  STAGE(0, 0);
  int cur = 0;
  for (int jt = 0; jt < qxA; ++jt) {     // interior tiles: mask-free
    __syncthreads();   // drains prev STAGE (vmcnt 0) + protects buf reuse
    STAGE(cur ^ 1, (jt + 1) * 64)
    attn_tile<false>(&Ks[cur][0], &Vs[cur][0], &Ksp[cur][0],
                     qa0A, qa1A, qspaA, jt * 64, qrow0A, nm, quad, ws, l_q, O);
    cur ^= 1;
  }
  // diagonal tile (masked) + phase-B tile-0 prefetch
  __syncthreads();
  STAGE(cur ^ 1, 0)
  attn_tile<true>(&Ks[cur][0], &Vs[cur][0], &Ksp[cur][0],
                  qa0A, qa1A, qspaA, qxA * 64, qrow0A, nm, quad, ws, l_q, O);
  cur ^= 1;

  // ---- epilogue A: 4-way combine (ws0 write, ws1-3 atomicAdd, ws0 store) ----
  {
    float lsum = l_q;
    lsum += __shfl_xor(lsum, 16);
    lsum += __shfl_xor(lsum, 32);
    if (quad == 0) Lxs[wr][ws][nm] = lsum;
  }
  if (ws == 0) {
#pragma unroll
    for (int dt = 0; dt < 4; ++dt)
#pragma unroll
      for (int r = 0; r < 4; ++r) Ox[wr][dt * 4 + r][lane] = O[dt][r];
  }
  __syncthreads();
  if (ws != 0) {
#pragma unroll
    for (int dt = 0; dt < 4; ++dt)
#pragma unroll
      for (int r = 0; r < 4; ++r) atomicAdd(&Ox[wr][dt * 4 + r][lane], O[dt][r]);
  }
  __syncthreads();
  if (ws == 0) {
#pragma unroll
    for (int r = 0; r < 4; ++r) {
      const int q = quad * 4 + r;
      const float tot = Lxs[wr][0][q] + Lxs[wr][1][q] + Lxs[wr][2][q] + Lxs[wr][3][q];
      const float inv = __builtin_amdgcn_rcpf(tot);
      const int rowg = qrow0A + q;
      unsigned short* orow = ao + ((size_t)b * 2048 + rowg) * 1024 + h * 64 + nm;
#pragma unroll
      for (int dt = 0; dt < 4; ++dt)
        orow[dt * 16] = f2bf(Ox[wr][dt * 4 + r][lane] * inv);
    }
  }
  // reset accumulators (all waves), AFTER all stores
#pragma unroll
  for (int dt = 0; dt < 4; ++dt) O[dt] = (f32x4){0.f, 0.f, 0.f, 0.f};
  l_q = 0.f;

  // ---------------- phase B (light q-tile) ----------------
  for (int jt = 0; jt < qxB; ++jt) {     // interior tiles
    __syncthreads();   // orders epilogue-A Ox/Lxs reads vs any reuse
    STAGE(cur ^ 1, (jt + 1) * 64)
    attn_tile<false>(&Ks[cur][0], &Vs[cur][0], &Ksp[cur][0],
                     qa0B, qa1B, qspaB, jt * 64, qrow0B, nm, quad, ws, l_q, O);
    cur ^= 1;
  }
  // diagonal tile (masked), no prefetch
  __syncthreads();   // protects buffer + separates epilogue-A LDS use
  attn_tile<true>(&Ks[cur][0], &Vs[cur][0], &Ksp[cur][0],
                  qa0B, qa1B, qspaB, qxB * 64, qrow0B, nm, quad, ws, l_q, O);

  // ---- epilogue B ----
  {
    float lsum = l_q;
    lsum += __shfl_xor(lsum, 16);
    lsum += __shfl_xor(lsum, 32);
    if (quad == 0) Lxs[wr][ws][nm] = lsum;
  }
  if (ws == 0) {
#pragma unroll
    for (int dt = 0; dt < 4; ++dt)
#pragma unroll
      for (int r = 0; r < 4; ++r) Ox[wr][dt * 4 + r][lane] = O[dt][r];
  }
  __syncthreads();
  if (ws != 0) {
#pragma unroll
    for (int dt = 0; dt < 4; ++dt)
#pragma unroll
      for (int r = 0; r < 4; ++r) atomicAdd(&Ox[wr][dt * 4 + r][lane], O[dt][r]);
  }
  __syncthreads();
  if (ws == 0) {
#pragma unroll
    for (int r = 0; r < 4; ++r) {
      const int q = quad * 4 + r;
      const float tot = Lxs[wr][0][q] + Lxs[wr][1][q] + Lxs[wr][2][q] + Lxs[wr][3][q];
      const float inv = __builtin_amdgcn_rcpf(tot);
      const int rowg = qrow0B + q;
      unsigned short* orow = ao + ((size_t)b * 2048 + rowg) * 1024 + h * 64 + nm;
#pragma unroll
      for (int dt = 0; dt < 4; ++dt)
        orow[dt * 16] = f2bf(Ox[wr][dt * 4 + r][lane] * inv);
    }
  }
#undef STAGE
}

// ---------------------------------------------------------------------------
extern "C" void kernel_launch(void* const* d_in, const int* in_sizes, int n_in,
                              void* d_out, int out_size, void* d_ws,
                              size_t ws_size, hipStream_t stream) {
  const float* x = (const float*)d_in[0];
  const float* Wq = (const float*)d_in[1];
  const float* Wk = (const float*)d_in[2];
  const float* Wv = (const float*)d_in[3];
  const float* Wo = (const float*)d_in[4];
  const float* bo = (const float*)d_in[5];
  const float* Ws = (const float*)d_in[6];
  const float* bs = (const float*)d_in[7];
  float* out = (float*)d_out;

  // Workspace layout (bytes):
  char* wsb = (char*)d_ws;
  float* proj = (float*)wsb;                                  // 25,165,824 B (dead after rope/vt)
  unsigned short* aob  = (unsigned short*)wsb;                // 8,388,608 B (alias proj head)
  unsigned short* qh   = (unsigned short*)(wsb + 25165824);   // 8,388,608 B
  unsigned short* kh   = (unsigned short*)(wsb + 33554432);   // 2,097,152 B
  unsigned short* vtb  = (unsigned short*)(wsb + 35651584);   // 2,097,152 B
  unsigned short* qsp  = (unsigned short*)(wsb + 37748736);   // 2,097,152 B
  unsigned short* ksp  = (unsigned short*)(wsb + 39845888);   //   524,288 B
  unsigned short* xb   = (unsigned short*)(wsb + 40370176);   // 8,388,608 B
  unsigned short* wqkv = (unsigned short*)(wsb + 48758784);   // 3,145,728 B
  unsigned short* wob  = (unsigned short*)(wsb + 51904512);   // 2,097,152 B

  convert_bf16<<<dim3(3328), 256, 0, stream>>>(x, Wq, Wk, Wv, Wo, xb, wqkv, wob);
  gemm_bf16<<<dim3(12, 64), 256, 0, stream>>>(xb, wqkv, nullptr, proj, 1536);
  rope_scatter<<<dim3(4096), 256, 0, stream>>>(proj, Ws, bs, qh, kh, qsp, ksp);
  v_transpose<<<dim3(32, 8), 256, 0, stream>>>(proj, vtb);
  attn_kernel<<<dim3(16, 32), 1024, 0, stream>>>(qh, kh, vtb, qsp, ksp, aob);
  gemm_bf16<<<dim3(8, 64), 256, 0, stream>>>(aob, wob, bo, out, 1024);
}

// Round 11
// 197.753 us; speedup vs baseline: 1.4265x; 1.4265x over previous
//
#include <hip/hip_runtime.h>
#include <math.h>

// Problem constants
#define B_ 2
#define S_ 2048
#define D_ 1024
#define H_ 16
#define HKV_ 4
#define HD_ 64
#define SD_ 16

typedef __attribute__((ext_vector_type(8))) short bf16x8;
typedef __attribute__((ext_vector_type(4))) float f32x4;
typedef __attribute__((ext_vector_type(8))) unsigned short us8;
typedef __attribute__((ext_vector_type(4))) unsigned short us4;

#define LOG2E 1.4426950408889634f

__device__ __forceinline__ unsigned short f2bf(float f) {
  unsigned int u = __builtin_bit_cast(unsigned int, f);
  u += 0x7fffu + ((u >> 16) & 1u);   // RNE; inputs are finite
  return (unsigned short)(u >> 16);
}

// global -> LDS async DMA, 16B per lane; LDS dest wave-uniform base + lane*16.
__device__ __forceinline__ void gload16(const unsigned short* g, unsigned short* l) {
  __builtin_amdgcn_global_load_lds(
      (const __attribute__((address_space(1))) unsigned int*)g,
      (__attribute__((address_space(3))) unsigned int*)l, 16, 0, 0);
}

// ---------------------------------------------------------------------------
// Kernel 0: fp32 -> bf16 convert for GEMM operands.
// ---------------------------------------------------------------------------
__global__ __launch_bounds__(256) void convert_bf16(
    const float* __restrict__ x, const float* __restrict__ wq,
    const float* __restrict__ wk, const float* __restrict__ wv,
    const float* __restrict__ wo, unsigned short* __restrict__ xb,
    unsigned short* __restrict__ wqkv, unsigned short* __restrict__ wob) {
  const int blk = blockIdx.x;
  const float* src;
  unsigned short* dst;
  int off;
  if (blk < 2048)      { src = x;  dst = xb;             off = blk * 2048; }
  else if (blk < 2560) { src = wq; dst = wqkv;           off = (blk - 2048) * 2048; }
  else if (blk < 2688) { src = wk; dst = wqkv + 1048576; off = (blk - 2560) * 2048; }
  else if (blk < 2816) { src = wv; dst = wqkv + 1310720; off = (blk - 2688) * 2048; }
  else                 { src = wo; dst = wob;            off = (blk - 2816) * 2048; }
  const int i = off + threadIdx.x * 8;
  float4 a = *(const float4*)(src + i);
  float4 b = *(const float4*)(src + i + 4);
  us8 o;
  o[0] = f2bf(a.x); o[1] = f2bf(a.y); o[2] = f2bf(a.z); o[3] = f2bf(a.w);
  o[4] = f2bf(b.x); o[5] = f2bf(b.y); o[6] = f2bf(b.z); o[7] = f2bf(b.w);
  *(us8*)(dst + i) = o;
}

// ---------------------------------------------------------------------------
// Kernel A/D: bf16 MFMA GEMM. R22: upsized 64x128 -> 128x128 tile (m93/m97
// structure: 4 waves in 2x2 quadrants, acc[4][4] per wave, same gload16
// staging + XOR swizzle as before). Per-FLOP staging bytes drop 33%; guide
// ladder puts this structure at 874-912 TF vs ~400 for the small tile.
// ---------------------------------------------------------------------------
__global__ __launch_bounds__(256) void gemm_bf16(
    const unsigned short* __restrict__ A, const unsigned short* __restrict__ Bm,
    const float* __restrict__ bias, float* __restrict__ C, int N) {
  __shared__ unsigned short As[128 * 64];
  __shared__ unsigned short Bs[128 * 64];
  const int tid = threadIdx.x;
  const int w = tid >> 6, lane = tid & 63;
  const int nm = lane & 15, quad = lane >> 4;
  const int m0 = blockIdx.y * 128, n0 = blockIdx.x * 128;
  const int wm = (w >> 1) * 64, wn = (w & 1) * 64;

  f32x4 acc[4][4] = {};
  int srow[4], scol[4];
#pragma unroll
  for (int it = 0; it < 4; ++it) {
    int s = it * 256 + tid;
    srow[it] = s >> 3;
    scol[it] = ((s & 7) ^ (srow[it] & 7)) * 8;
  }

  for (int k0 = 0; k0 < 1024; k0 += 64) {
    __syncthreads();
#pragma unroll
    for (int it = 0; it < 4; ++it) {
      gload16(A + (size_t)(m0 + srow[it]) * 1024 + k0 + scol[it],
              &As[(it * 256 + w * 64) * 8]);
      gload16(Bm + (size_t)(n0 + srow[it]) * 1024 + k0 + scol[it],
              &Bs[(it * 256 + w * 64) * 8]);
    }
    __syncthreads();

#pragma unroll
    for (int ks = 0; ks < 2; ++ks) {
      const int cq = ks * 4 + quad;
      bf16x8 af[4], bfr[4];
#pragma unroll
      for (int mi = 0; mi < 4; ++mi) {
        const int m = wm + mi * 16 + nm;
        af[mi] = *(const bf16x8*)&As[(m * 8 + (cq ^ (m & 7))) * 8];
      }
#pragma unroll
      for (int ni = 0; ni < 4; ++ni) {
        const int n = wn + ni * 16 + nm;
        bfr[ni] = *(const bf16x8*)&Bs[(n * 8 + (cq ^ (n & 7))) * 8];
      }
#pragma unroll
      for (int mi = 0; mi < 4; ++mi)
#pragma unroll
        for (int ni = 0; ni < 4; ++ni)
          acc[mi][ni] = __builtin_amdgcn_mfma_f32_16x16x32_bf16(
              af[mi], bfr[ni], acc[mi][ni], 0, 0, 0);
    }
  }

  float bv[4] = {0.f, 0.f, 0.f, 0.f};
  if (bias) {
#pragma unroll
    for (int ni = 0; ni < 4; ++ni) bv[ni] = bias[n0 + wn + ni * 16 + nm];
  }
#pragma unroll
  for (int mi = 0; mi < 4; ++mi) {
#pragma unroll
    for (int r = 0; r < 4; ++r) {
      const int row = m0 + wm + mi * 16 + quad * 4 + r;
      float* crow = C + (size_t)row * N + n0 + wn + nm;
#pragma unroll
      for (int ni = 0; ni < 4; ++ni) crow[ni * 16] = acc[mi][ni][r] + bv[ni];
    }
  }
}

// ---------------------------------------------------------------------------
// Kernel B: RoPE + scatter (bf16) + low-rank sparsity proj (slots 0..19).
// q scaled by log2e/8, qsp by log2e/4 so attn uses native exp2.
// ---------------------------------------------------------------------------
__global__ __launch_bounds__(256) void rope_scatter(
    const float* __restrict__ P, const float* __restrict__ Ws,
    const float* __restrict__ bs, unsigned short* __restrict__ qh,
    unsigned short* __restrict__ kh, unsigned short* __restrict__ qsp,
    unsigned short* __restrict__ ksp) {
  __shared__ float wsl[16 * 64];
  __shared__ float bsl[16];
  __shared__ float rbuf[4][64];
  const int tid = threadIdx.x;
  const int row = blockIdx.x;
  const int b = row >> 11;
  const int s = row & 2047;
  {
    *(float4*)&wsl[tid * 4] = *(const float4*)&Ws[tid * 4];
    if (tid < 16) bsl[tid] = bs[tid];
  }
  __syncthreads();
  const int w = tid >> 6, lane = tid & 63;
  const int i = lane & 31, halfu = lane >> 5;
  const float theta = powf(10000.f, -((float)(2 * i) * (1.f / 64.f)));
  const float f = (float)s * theta;
  const float cf = cosf(f);
  const float sf = sinf(f);
  for (int slot = w; slot < 20; slot += 4) {
    float val = P[(size_t)row * 1536 + slot * 64 + lane];
    float partner = __shfl_xor(val, 32);
    float rot = halfu ? partner : -partner;
    float r = val * cf + rot * sf;
    unsigned short* dst;
    unsigned short* spdst;
    float qscale, spscale;
    if (slot < 16) {
      dst = qh + ((size_t)(b * 16 + slot) * 2048 + s) * 64;
      spdst = qsp + ((size_t)(b * 16 + slot) * 2048 + s) * 16;
      qscale = 0.125f * LOG2E; spscale = 0.25f * LOG2E;
    } else {
      int hh = slot - 16;
      dst = kh + ((size_t)(b * 4 + hh) * 2048 + s) * 64;
      spdst = ksp + ((size_t)(b * 4 + hh) * 2048 + s) * 16;
      qscale = 1.f; spscale = 1.f;
    }
    dst[lane] = f2bf(r * qscale);
    rbuf[w][lane] = r;
    int p = lane >> 4, j = lane & 15;
    float partial = 0.f;
#pragma unroll
    for (int t = 0; t < 16; ++t)
      partial += wsl[j * 64 + p * 16 + t] * rbuf[w][p * 16 + t];
    partial += __shfl_xor(partial, 16);
    partial += __shfl_xor(partial, 32);
    if (p == 0) spdst[j] = f2bf((partial + bsl[j]) * spscale);
  }
}

// ---------------------------------------------------------------------------
// Kernel B2: one-time V transpose: proj v-cols (f32) -> vt[bkv][d=64][s=2048] bf16.
// ---------------------------------------------------------------------------
__global__ __launch_bounds__(256) void v_transpose(
    const float* __restrict__ proj, unsigned short* __restrict__ vt) {
  __shared__ unsigned short t_[64 * 72];
  const int bkv = blockIdx.y;
  const int s0 = blockIdx.x * 64;
  const int b = bkv >> 2, hkv = bkv & 3;
  const int tid = threadIdx.x;
  const int sl = tid >> 2;
  const int c0 = (tid & 3) * 16;
  const float* src = proj + ((size_t)b * 2048 + s0 + sl) * 1536 + 1280 + hkv * 64 + c0;
  us8 o0, o1;
#pragma unroll
  for (int t = 0; t < 8; ++t) { o0[t] = f2bf(src[t]); o1[t] = f2bf(src[8 + t]); }
  *(us8*)&t_[sl * 72 + c0] = o0;
  *(us8*)&t_[sl * 72 + c0 + 8] = o1;
  __syncthreads();
  const int d = tid >> 2;
  const int sc_ = (tid & 3) * 16;
  us8 w0, w1;
#pragma unroll
  for (int t = 0; t < 8; ++t) w0[t] = t_[(sc_ + t) * 72 + d];
#pragma unroll
  for (int t = 0; t < 8; ++t) w1[t] = t_[(sc_ + 8 + t) * 72 + d];
  unsigned short* dst = vt + (size_t)bkv * 131072 + (size_t)d * 2048 + s0 + sc_;
  *(us8*)dst = w0;
  *(us8*)(dst + 8) = w1;
}

// ---------------------------------------------------------------------------
// Kernel C: gated causal flash attention.
// R22: attn reverted VERBATIM to R17 (best measured: 57.2 us). R20's
// counted-vmcnt graft (-48%) and R21's 16-wave block (VGPR clamp -> scratch
// spill, WRITE_SIZE 8->64 MB) both regressed; the R17 structure (8-wave
// key-split, 2-phase pipeline, mask peel) is the proven local optimum.
// ---------------------------------------------------------------------------
template <bool MASK>
__device__ __forceinline__ void attn_tile(
    const unsigned short* __restrict__ Ksb, const unsigned short* __restrict__ Vsb,
    const unsigned short* __restrict__ Kspb_, unsigned short* __restrict__ pw,
    bf16x8 qa0, bf16x8 qa1, bf16x8 qspa, int j0, int qrow0, int nm, int quad,
    int ws, float l_r[4], f32x4 O[4]) {
  // ---- QK^T + gate -> p = exp2(s'*gate), accumulate l, write P ----
  // This wave handles key groups st = ws*2 + {0,1} (32 keys).
#pragma unroll
  for (int stl = 0; stl < 2; ++stl) {
    const int st = ws * 2 + stl;
    if (MASK && (j0 + st * 16 > qrow0 + 15)) {
      // fully-masked key group: zero P, skip the math
#pragma unroll
      for (int r = 0; r < 4; ++r) {
        const int prow = quad * 4 + r;
        const int chunk = (stl * 2 + (nm >> 3)) ^ ((prow ^ (prow >> 2)) & 3);
        pw[(prow * 4 + chunk) * 8 + (nm & 7)] = 0;
      }
      continue;
    }
    const int krow = st * 16 + nm;
    const int r7 = krow & 7;
    bf16x8 kb0 = *(const bf16x8*)&Ksb[(krow * 8 + (quad ^ r7)) * 8];
    bf16x8 kb1 = *(const bf16x8*)&Ksb[(krow * 8 + ((4 + quad) ^ r7)) * 8];
    bf16x8 gb = *(const bf16x8*)&Kspb_[(krow * 2 + (quad & 1)) * 8];
    f32x4 z = {0.f, 0.f, 0.f, 0.f};
    f32x4 s = __builtin_amdgcn_mfma_f32_16x16x32_bf16(qa0, kb0, z, 0, 0, 0);
    s = __builtin_amdgcn_mfma_f32_16x16x32_bf16(qa1, kb1, s, 0, 0, 0);
    f32x4 g = __builtin_amdgcn_mfma_f32_16x16x32_bf16(qspa, gb, z, 0, 0, 0);
#pragma unroll
    for (int r = 0; r < 4; ++r) {
      // sigmoid via raw v_rcp + v_exp (g pre-scaled by log2e)
      float gate = __builtin_amdgcn_rcpf(1.f + __builtin_amdgcn_exp2f(-g[r]));
      float v = s[r] * gate;                   // s pre-scaled by log2e
      if (MASK) {
        const bool edge = (j0 + st * 16 + 15 > qrow0);
        if (edge) {
          const int col = j0 + st * 16 + nm;
          const int rowg = qrow0 + quad * 4 + r;
          v = (col > rowg) ? -INFINITY : v;
        }
      }
      float p = __builtin_amdgcn_exp2f(v);     // exp2(-inf) == 0
      l_r[r] += p;
      const int prow = quad * 4 + r;
      const int chunk = (stl * 2 + (nm >> 3)) ^ ((prow ^ (prow >> 2)) & 3);
      pw[(prow * 4 + chunk) * 8 + (nm & 7)] = f2bf(p);
    }
  }

  // ---- PV (this wave's 32-key half): one k=32 MFMA per d-tile ----
  bf16x8 pa = *(const bf16x8*)&pw[(nm * 4 + (quad ^ ((nm ^ (nm >> 2)) & 3))) * 8];
#pragma unroll
  for (int dt = 0; dt < 4; ++dt) {
    const int vrow = dt * 16 + nm;
    bf16x8 vb = *(const bf16x8*)&Vsb[(vrow * 8 + ((ws * 4 + quad) ^ (vrow & 7))) * 8];
    O[dt] = __builtin_amdgcn_mfma_f32_16x16x32_bf16(pa, vb, O[dt], 0, 0, 0);
  }
}

__global__ __launch_bounds__(512) void attn_kernel(
    const unsigned short* __restrict__ qh, const unsigned short* __restrict__ kh,
    const unsigned short* __restrict__ vt, const unsigned short* __restrict__ qsp,
    const unsigned short* __restrict__ ksp, unsigned short* __restrict__ ao) {
  __shared__ unsigned short Ks[2][64 * 64];
  __shared__ unsigned short Vs[2][64 * 64];
  __shared__ unsigned short Ksp[2][64 * 16];
  __shared__ unsigned short Pw[8][16 * 32];
  __shared__ float Ox[4][16][64];   // [row-group][dt*4+r][lane] exchange
  __shared__ float Lx[4][4][64];

  const int tid = threadIdx.x;
  const int w = tid >> 6;       // 0..7
  const int ws = w >> 2;        // key-half: 0 -> keys 0-31, 1 -> keys 32-63
  const int wr = w & 3;         // q-row group (16 rows)
  const int lane = tid & 63;
  const int nm = lane & 15;
  const int quad = lane >> 4;
  const int bh = blockIdx.y;
  const int b = bh >> 4, h = bh & 15;
  const int hkv = h >> 2;
  const size_t kbase = (size_t)(b * 4 + hkv) * 2048 * 64;
  const size_t vbase = (size_t)(b * 4 + hkv) * 131072;
  const size_t kspb = (size_t)(b * 4 + hkv) * 2048 * 16;

  // staging coords: 512 lanes cover the 64x64 tile in one pass
  const int Lc = tid;
  const int sr = Lc >> 3;
  const int sc = ((Lc & 7) ^ (sr & 7)) * 8;
  unsigned short* pw = &Pw[w][0];

#define STAGE(BUF, J0)                                                         \
  {                                                                            \
    gload16(kh + kbase + (size_t)((J0) + sr) * 64 + sc,                        \
            &Ks[BUF][(w * 64) * 8]);                                           \
    gload16(vt + vbase + (size_t)sr * 2048 + (J0) + sc,                        \
            &Vs[BUF][(w * 64) * 8]);                                           \
    if (w < 2) {                                                               \
      gload16(ksp + kspb + (size_t)((J0) + (Lc >> 1)) * 16 + (Lc & 1) * 8,     \
              &Ksp[BUF][w * 512]);                                             \
    }                                                                          \
  }

  const int qxA = 31 - blockIdx.x;  // heavy tile
  const int qxB = blockIdx.x;       // light tile
  const int qrow0A = qxA * 64 + wr * 16;
  const int qrow0B = qxB * 64 + wr * 16;

  // q fragments for both phases (row group wr; both key-halves use the same Q)
  const size_t qbA = ((size_t)(b * 16 + h) * 2048 + qrow0A + nm) * 64;
  bf16x8 qa0A = *(const bf16x8*)(qh + qbA + quad * 8);
  bf16x8 qa1A = *(const bf16x8*)(qh + qbA + 32 + quad * 8);
  const size_t qbB = ((size_t)(b * 16 + h) * 2048 + qrow0B + nm) * 64;
  bf16x8 qa0B = *(const bf16x8*)(qh + qbB + quad * 8);
  bf16x8 qa1B = *(const bf16x8*)(qh + qbB + 32 + quad * 8);
  bf16x8 qspaA = {0, 0, 0, 0, 0, 0, 0, 0};
  bf16x8 qspaB = {0, 0, 0, 0, 0, 0, 0, 0};
  if (quad < 2) {
    qspaA = *(const bf16x8*)(qsp + ((size_t)(b * 16 + h) * 2048 + qrow0A + nm) * 16 + quad * 8);
    qspaB = *(const bf16x8*)(qsp + ((size_t)(b * 16 + h) * 2048 + qrow0B + nm) * 16 + quad * 8);
  }

  float l_r[4] = {0.f, 0.f, 0.f, 0.f};
  f32x4 O[4] = {{0.f, 0.f, 0.f, 0.f}, {0.f, 0.f, 0.f, 0.f},
                {0.f, 0.f, 0.f, 0.f}, {0.f, 0.f, 0.f, 0.f}};

  // ---------------- phase A (heavy q-tile), pipelined ----------------
  STAGE(0, 0);
  int cur = 0;
  for (int jt = 0; jt < qxA; ++jt) {     // interior tiles: mask-free for all waves
    __syncthreads();   // drains prev STAGE (vmcnt 0) + protects buf reuse
    STAGE(cur ^ 1, (jt + 1) * 64)
    attn_tile<false>(&Ks[cur][0], &Vs[cur][0], &Ksp[cur][0], pw,
                     qa0A, qa1A, qspaA, jt * 64, qrow0A, nm, quad, ws, l_r, O);
    cur ^= 1;
  }
  // diagonal tile jt == qxA (masked) + phase-B tile-0 prefetch
  __syncthreads();
  STAGE(cur ^ 1, 0)
  attn_tile<true>(&Ks[cur][0], &Vs[cur][0], &Ksp[cur][0], pw,
                  qa0A, qa1A, qspaA, qxA * 64, qrow0A, nm, quad, ws, l_r, O);
  cur ^= 1;

  // ---- epilogue A: combine key-halves, store (overlaps B tile-0 DMA) ----
  if (ws == 1) {
#pragma unroll
    for (int dt = 0; dt < 4; ++dt)
#pragma unroll
      for (int r = 0; r < 4; ++r) Ox[wr][dt * 4 + r][lane] = O[dt][r];
#pragma unroll
    for (int r = 0; r < 4; ++r) Lx[wr][r][lane] = l_r[r];
  }
  __syncthreads();
  if (ws == 0) {
#pragma unroll
    for (int r = 0; r < 4; ++r) {
      float v = l_r[r] + Lx[wr][r][lane];
      v += __shfl_xor(v, 1);
      v += __shfl_xor(v, 2);
      v += __shfl_xor(v, 4);
      v += __shfl_xor(v, 8);
      const float inv = __builtin_amdgcn_rcpf(v);
      const int rowg = qrow0A + quad * 4 + r;
      unsigned short* orow = ao + ((size_t)b * 2048 + rowg) * 1024 + h * 64 + nm;
#pragma unroll
      for (int dt = 0; dt < 4; ++dt)
        orow[dt * 16] = f2bf((O[dt][r] + Ox[wr][dt * 4 + r][lane]) * inv);
    }
  }
  // reset accumulators (all waves), AFTER all stores
#pragma unroll
  for (int dt = 0; dt < 4; ++dt) O[dt] = (f32x4){0.f, 0.f, 0.f, 0.f};
#pragma unroll
  for (int r = 0; r < 4; ++r) l_r[r] = 0.f;

  // ---------------- phase B (light q-tile), pipelined ----------------
  for (int jt = 0; jt < qxB; ++jt) {     // interior tiles
    __syncthreads();   // also orders epilogue-A Ox reads vs phase-B writes
    STAGE(cur ^ 1, (jt + 1) * 64)
    attn_tile<false>(&Ks[cur][0], &Vs[cur][0], &Ksp[cur][0], pw,
                     qa0B, qa1B, qspaB, jt * 64, qrow0B, nm, quad, ws, l_r, O);
    cur ^= 1;
  }
  // diagonal tile jt == qxB (masked), no prefetch
  __syncthreads();
  attn_tile<true>(&Ks[cur][0], &Vs[cur][0], &Ksp[cur][0], pw,
                  qa0B, qa1B, qspaB, qxB * 64, qrow0B, nm, quad, ws, l_r, O);

  // ---- epilogue B ----
  if (ws == 1) {
#pragma unroll
    for (int dt = 0; dt < 4; ++dt)
#pragma unroll
      for (int r = 0; r < 4; ++r) Ox[wr][dt * 4 + r][lane] = O[dt][r];
#pragma unroll
    for (int r = 0; r < 4; ++r) Lx[wr][r][lane] = l_r[r];
  }
  __syncthreads();
  if (ws == 0) {
#pragma unroll
    for (int r = 0; r < 4; ++r) {
      float v = l_r[r] + Lx[wr][r][lane];
      v += __shfl_xor(v, 1);
      v += __shfl_xor(v, 2);
      v += __shfl_xor(v, 4);
      v += __shfl_xor(v, 8);
      const float inv = __builtin_amdgcn_rcpf(v);
      const int rowg = qrow0B + quad * 4 + r;
      unsigned short* orow = ao + ((size_t)b * 2048 + rowg) * 1024 + h * 64 + nm;
#pragma unroll
      for (int dt = 0; dt < 4; ++dt)
        orow[dt * 16] = f2bf((O[dt][r] + Ox[wr][dt * 4 + r][lane]) * inv);
    }
  }
#undef STAGE
}

// ---------------------------------------------------------------------------
extern "C" void kernel_launch(void* const* d_in, const int* in_sizes, int n_in,
                              void* d_out, int out_size, void* d_ws,
                              size_t ws_size, hipStream_t stream) {
  const float* x = (const float*)d_in[0];
  const float* Wq = (const float*)d_in[1];
  const float* Wk = (const float*)d_in[2];
  const float* Wv = (const float*)d_in[3];
  const float* Wo = (const float*)d_in[4];
  const float* bo = (const float*)d_in[5];
  const float* Ws = (const float*)d_in[6];
  const float* bs = (const float*)d_in[7];
  float* out = (float*)d_out;

  // Workspace layout (bytes):
  char* wsb = (char*)d_ws;
  float* proj = (float*)wsb;                                  // 25,165,824 B (dead after rope/vt)
  unsigned short* aob  = (unsigned short*)wsb;                // 8,388,608 B (alias proj head)
  unsigned short* qh   = (unsigned short*)(wsb + 25165824);   // 8,388,608 B
  unsigned short* kh   = (unsigned short*)(wsb + 33554432);   // 2,097,152 B
  unsigned short* vtb  = (unsigned short*)(wsb + 35651584);   // 2,097,152 B
  unsigned short* qsp  = (unsigned short*)(wsb + 37748736);   // 2,097,152 B
  unsigned short* ksp  = (unsigned short*)(wsb + 39845888);   //   524,288 B
  unsigned short* xb   = (unsigned short*)(wsb + 40370176);   // 8,388,608 B
  unsigned short* wqkv = (unsigned short*)(wsb + 48758784);   // 3,145,728 B
  unsigned short* wob  = (unsigned short*)(wsb + 51904512);   // 2,097,152 B

  convert_bf16<<<dim3(3328), 256, 0, stream>>>(x, Wq, Wk, Wv, Wo, xb, wqkv, wob);
  gemm_bf16<<<dim3(12, 32), 256, 0, stream>>>(xb, wqkv, nullptr, proj, 1536);
  rope_scatter<<<dim3(4096), 256, 0, stream>>>(proj, Ws, bs, qh, kh, qsp, ksp);
  v_transpose<<<dim3(32, 8), 256, 0, stream>>>(proj, vtb);
  attn_kernel<<<dim3(16, 32), 512, 0, stream>>>(qh, kh, vtb, qsp, ksp, aob);
  gemm_bf16<<<dim3(8, 32), 256, 0, stream>>>(aob, wob, bo, out, 1024);
}

// Round 12
// 194.610 us; speedup vs baseline: 1.4495x; 1.0162x over previous
//
#include <hip/hip_runtime.h>
#include <math.h>

// Problem constants
#define B_ 2
#define S_ 2048
#define D_ 1024
#define H_ 16
#define HKV_ 4
#define HD_ 64
#define SD_ 16

typedef __attribute__((ext_vector_type(8))) short bf16x8;
typedef __attribute__((ext_vector_type(4))) float f32x4;
typedef __attribute__((ext_vector_type(8))) unsigned short us8;
typedef __attribute__((ext_vector_type(4))) unsigned short us4;

#define LOG2E 1.4426950408889634f

__device__ __forceinline__ unsigned short f2bf(float f) {
  unsigned int u = __builtin_bit_cast(unsigned int, f);
  u += 0x7fffu + ((u >> 16) & 1u);   // RNE; inputs are finite
  return (unsigned short)(u >> 16);
}

// global -> LDS async DMA, 16B per lane; LDS dest wave-uniform base + lane*16.
__device__ __forceinline__ void gload16(const unsigned short* g, unsigned short* l) {
  __builtin_amdgcn_global_load_lds(
      (const __attribute__((address_space(1))) unsigned int*)g,
      (__attribute__((address_space(3))) unsigned int*)l, 16, 0, 0);
}

// ---------------------------------------------------------------------------
// Kernel 0: fp32 -> bf16 convert for GEMM operands.
// ---------------------------------------------------------------------------
__global__ __launch_bounds__(256) void convert_bf16(
    const float* __restrict__ x, const float* __restrict__ wq,
    const float* __restrict__ wk, const float* __restrict__ wv,
    const float* __restrict__ wo, unsigned short* __restrict__ xb,
    unsigned short* __restrict__ wqkv, unsigned short* __restrict__ wob) {
  const int blk = blockIdx.x;
  const float* src;
  unsigned short* dst;
  int off;
  if (blk < 2048)      { src = x;  dst = xb;             off = blk * 2048; }
  else if (blk < 2560) { src = wq; dst = wqkv;           off = (blk - 2048) * 2048; }
  else if (blk < 2688) { src = wk; dst = wqkv + 1048576; off = (blk - 2560) * 2048; }
  else if (blk < 2816) { src = wv; dst = wqkv + 1310720; off = (blk - 2688) * 2048; }
  else                 { src = wo; dst = wob;            off = (blk - 2816) * 2048; }
  const int i = off + threadIdx.x * 8;
  float4 a = *(const float4*)(src + i);
  float4 b = *(const float4*)(src + i + 4);
  us8 o;
  o[0] = f2bf(a.x); o[1] = f2bf(a.y); o[2] = f2bf(a.z); o[3] = f2bf(a.w);
  o[4] = f2bf(b.x); o[5] = f2bf(b.y); o[6] = f2bf(b.z); o[7] = f2bf(b.w);
  *(us8*)(dst + i) = o;
}

// ---------------------------------------------------------------------------
// Kernel A: bf16 MFMA GEMM, 64x128 tile (m97 staging). R23: restored for
// gemm1 (M=4096,N=1536): grid (12,64)=768 blocks = 3.0 balanced rounds on
// 256 CUs. R22's 128^2 tile gave 384 blocks = 1.5 rounds -> half-idle round
// 2, +10.8 us measured. Tile choice must respect grid/CU divisibility.
// ---------------------------------------------------------------------------
__global__ __launch_bounds__(256) void gemm_bf16(
    const unsigned short* __restrict__ A, const unsigned short* __restrict__ Bm,
    const float* __restrict__ bias, float* __restrict__ C, int N) {
  __shared__ unsigned short As[64 * 64];
  __shared__ unsigned short Bs[128 * 64];
  const int tid = threadIdx.x;
  const int w = tid >> 6, lane = tid & 63;
  const int nm = lane & 15, quad = lane >> 4;
  const int m0 = blockIdx.y * 64, n0 = blockIdx.x * 128;
  const int wn = w * 32;

  f32x4 acc[4][2] = {};
  int arow[2], acol[2], brow[4], bcol[4];
#pragma unroll
  for (int it = 0; it < 2; ++it) {
    int s = it * 256 + tid;
    arow[it] = s >> 3;
    acol[it] = ((s & 7) ^ (arow[it] & 7)) * 8;
  }
#pragma unroll
  for (int it = 0; it < 4; ++it) {
    int s = it * 256 + tid;
    brow[it] = s >> 3;
    bcol[it] = ((s & 7) ^ (brow[it] & 7)) * 8;
  }

  for (int k0 = 0; k0 < 1024; k0 += 64) {
    __syncthreads();
#pragma unroll
    for (int it = 0; it < 2; ++it)
      gload16(A + (size_t)(m0 + arow[it]) * 1024 + k0 + acol[it],
              &As[(it * 256 + w * 64) * 8]);
#pragma unroll
    for (int it = 0; it < 4; ++it)
      gload16(Bm + (size_t)(n0 + brow[it]) * 1024 + k0 + bcol[it],
              &Bs[(it * 256 + w * 64) * 8]);
    __syncthreads();

#pragma unroll
    for (int ks = 0; ks < 2; ++ks) {
      const int cq = ks * 4 + quad;
      bf16x8 af[4], bfr[2];
#pragma unroll
      for (int mi = 0; mi < 4; ++mi) {
        const int m = mi * 16 + nm;
        af[mi] = *(const bf16x8*)&As[(m * 8 + (cq ^ (m & 7))) * 8];
      }
#pragma unroll
      for (int ni = 0; ni < 2; ++ni) {
        const int n = wn + ni * 16 + nm;
        bfr[ni] = *(const bf16x8*)&Bs[(n * 8 + (cq ^ (n & 7))) * 8];
      }
#pragma unroll
      for (int mi = 0; mi < 4; ++mi)
#pragma unroll
        for (int ni = 0; ni < 2; ++ni)
          acc[mi][ni] = __builtin_amdgcn_mfma_f32_16x16x32_bf16(
              af[mi], bfr[ni], acc[mi][ni], 0, 0, 0);
    }
  }

  float bv[2] = {0.f, 0.f};
  if (bias) {
#pragma unroll
    for (int ni = 0; ni < 2; ++ni) bv[ni] = bias[n0 + wn + ni * 16 + nm];
  }
#pragma unroll
  for (int mi = 0; mi < 4; ++mi) {
#pragma unroll
    for (int r = 0; r < 4; ++r) {
      const int row = m0 + mi * 16 + quad * 4 + r;
      float* crow = C + (size_t)row * N + n0 + wn + nm;
#pragma unroll
      for (int ni = 0; ni < 2; ++ni) crow[ni * 16] = acc[mi][ni][r] + bv[ni];
    }
  }
}

// ---------------------------------------------------------------------------
// Kernel D: bf16 MFMA GEMM, 128x128 tile (m93/m97 structure). Used ONLY for
// gemm2 (M=4096,N=1024): grid (8,32)=256 blocks = exactly 1.0 round on 256
// CUs — balanced AND 33% fewer staging bytes/FLOP than the 64x128 tile.
// ---------------------------------------------------------------------------
__global__ __launch_bounds__(256) void gemm_bf16_128(
    const unsigned short* __restrict__ A, const unsigned short* __restrict__ Bm,
    const float* __restrict__ bias, float* __restrict__ C, int N) {
  __shared__ unsigned short As[128 * 64];
  __shared__ unsigned short Bs[128 * 64];
  const int tid = threadIdx.x;
  const int w = tid >> 6, lane = tid & 63;
  const int nm = lane & 15, quad = lane >> 4;
  const int m0 = blockIdx.y * 128, n0 = blockIdx.x * 128;
  const int wm = (w >> 1) * 64, wn = (w & 1) * 64;

  f32x4 acc[4][4] = {};
  int srow[4], scol[4];
#pragma unroll
  for (int it = 0; it < 4; ++it) {
    int s = it * 256 + tid;
    srow[it] = s >> 3;
    scol[it] = ((s & 7) ^ (srow[it] & 7)) * 8;
  }

  for (int k0 = 0; k0 < 1024; k0 += 64) {
    __syncthreads();
#pragma unroll
    for (int it = 0; it < 4; ++it) {
      gload16(A + (size_t)(m0 + srow[it]) * 1024 + k0 + scol[it],
              &As[(it * 256 + w * 64) * 8]);
      gload16(Bm + (size_t)(n0 + srow[it]) * 1024 + k0 + scol[it],
              &Bs[(it * 256 + w * 64) * 8]);
    }
    __syncthreads();

#pragma unroll
    for (int ks = 0; ks < 2; ++ks) {
      const int cq = ks * 4 + quad;
      bf16x8 af[4], bfr[4];
#pragma unroll
      for (int mi = 0; mi < 4; ++mi) {
        const int m = wm + mi * 16 + nm;
        af[mi] = *(const bf16x8*)&As[(m * 8 + (cq ^ (m & 7))) * 8];
      }
#pragma unroll
      for (int ni = 0; ni < 4; ++ni) {
        const int n = wn + ni * 16 + nm;
        bfr[ni] = *(const bf16x8*)&Bs[(n * 8 + (cq ^ (n & 7))) * 8];
      }
#pragma unroll
      for (int mi = 0; mi < 4; ++mi)
#pragma unroll
        for (int ni = 0; ni < 4; ++ni)
          acc[mi][ni] = __builtin_amdgcn_mfma_f32_16x16x32_bf16(
              af[mi], bfr[ni], acc[mi][ni], 0, 0, 0);
    }
  }

  float bv[4] = {0.f, 0.f, 0.f, 0.f};
  if (bias) {
#pragma unroll
    for (int ni = 0; ni < 4; ++ni) bv[ni] = bias[n0 + wn + ni * 16 + nm];
  }
#pragma unroll
  for (int mi = 0; mi < 4; ++mi) {
#pragma unroll
    for (int r = 0; r < 4; ++r) {
      const int row = m0 + wm + mi * 16 + quad * 4 + r;
      float* crow = C + (size_t)row * N + n0 + wn + nm;
#pragma unroll
      for (int ni = 0; ni < 4; ++ni) crow[ni * 16] = acc[mi][ni][r] + bv[ni];
    }
  }
}

// ---------------------------------------------------------------------------
// Kernel B: RoPE + scatter (bf16) + low-rank sparsity proj (slots 0..19).
// q scaled by log2e/8, qsp by log2e/4 so attn uses native exp2.
// ---------------------------------------------------------------------------
__global__ __launch_bounds__(256) void rope_scatter(
    const float* __restrict__ P, const float* __restrict__ Ws,
    const float* __restrict__ bs, unsigned short* __restrict__ qh,
    unsigned short* __restrict__ kh, unsigned short* __restrict__ qsp,
    unsigned short* __restrict__ ksp) {
  __shared__ float wsl[16 * 64];
  __shared__ float bsl[16];
  __shared__ float rbuf[4][64];
  const int tid = threadIdx.x;
  const int row = blockIdx.x;
  const int b = row >> 11;
  const int s = row & 2047;
  {
    *(float4*)&wsl[tid * 4] = *(const float4*)&Ws[tid * 4];
    if (tid < 16) bsl[tid] = bs[tid];
  }
  __syncthreads();
  const int w = tid >> 6, lane = tid & 63;
  const int i = lane & 31, halfu = lane >> 5;
  const float theta = powf(10000.f, -((float)(2 * i) * (1.f / 64.f)));
  const float f = (float)s * theta;
  const float cf = cosf(f);
  const float sf = sinf(f);
  for (int slot = w; slot < 20; slot += 4) {
    float val = P[(size_t)row * 1536 + slot * 64 + lane];
    float partner = __shfl_xor(val, 32);
    float rot = halfu ? partner : -partner;
    float r = val * cf + rot * sf;
    unsigned short* dst;
    unsigned short* spdst;
    float qscale, spscale;
    if (slot < 16) {
      dst = qh + ((size_t)(b * 16 + slot) * 2048 + s) * 64;
      spdst = qsp + ((size_t)(b * 16 + slot) * 2048 + s) * 16;
      qscale = 0.125f * LOG2E; spscale = 0.25f * LOG2E;
    } else {
      int hh = slot - 16;
      dst = kh + ((size_t)(b * 4 + hh) * 2048 + s) * 64;
      spdst = ksp + ((size_t)(b * 4 + hh) * 2048 + s) * 16;
      qscale = 1.f; spscale = 1.f;
    }
    dst[lane] = f2bf(r * qscale);
    rbuf[w][lane] = r;
    int p = lane >> 4, j = lane & 15;
    float partial = 0.f;
#pragma unroll
    for (int t = 0; t < 16; ++t)
      partial += wsl[j * 64 + p * 16 + t] * rbuf[w][p * 16 + t];
    partial += __shfl_xor(partial, 16);
    partial += __shfl_xor(partial, 32);
    if (p == 0) spdst[j] = f2bf((partial + bsl[j]) * spscale);
  }
}

// ---------------------------------------------------------------------------
// Kernel B2: one-time V transpose: proj v-cols (f32) -> vt[bkv][d=64][s=2048] bf16.
// ---------------------------------------------------------------------------
__global__ __launch_bounds__(256) void v_transpose(
    const float* __restrict__ proj, unsigned short* __restrict__ vt) {
  __shared__ unsigned short t_[64 * 72];
  const int bkv = blockIdx.y;
  const int s0 = blockIdx.x * 64;
  const int b = bkv >> 2, hkv = bkv & 3;
  const int tid = threadIdx.x;
  const int sl = tid >> 2;
  const int c0 = (tid & 3) * 16;
  const float* src = proj + ((size_t)b * 2048 + s0 + sl) * 1536 + 1280 + hkv * 64 + c0;
  us8 o0, o1;
#pragma unroll
  for (int t = 0; t < 8; ++t) { o0[t] = f2bf(src[t]); o1[t] = f2bf(src[8 + t]); }
  *(us8*)&t_[sl * 72 + c0] = o0;
  *(us8*)&t_[sl * 72 + c0 + 8] = o1;
  __syncthreads();
  const int d = tid >> 2;
  const int sc_ = (tid & 3) * 16;
  us8 w0, w1;
#pragma unroll
  for (int t = 0; t < 8; ++t) w0[t] = t_[(sc_ + t) * 72 + d];
#pragma unroll
  for (int t = 0; t < 8; ++t) w1[t] = t_[(sc_ + 8 + t) * 72 + d];
  unsigned short* dst = vt + (size_t)bkv * 131072 + (size_t)d * 2048 + s0 + sc_;
  *(us8*)dst = w0;
  *(us8*)(dst + 8) = w1;
}

// ---------------------------------------------------------------------------
// Kernel C: gated causal flash attention. Verbatim R17 (proven 57.2 us):
// 8-wave key-split, 2-phase pipeline, mask peel.
// ---------------------------------------------------------------------------
template <bool MASK>
__device__ __forceinline__ void attn_tile(
    const unsigned short* __restrict__ Ksb, const unsigned short* __restrict__ Vsb,
    const unsigned short* __restrict__ Kspb_, unsigned short* __restrict__ pw,
    bf16x8 qa0, bf16x8 qa1, bf16x8 qspa, int j0, int qrow0, int nm, int quad,
    int ws, float l_r[4], f32x4 O[4]) {
  // ---- QK^T + gate -> p = exp2(s'*gate), accumulate l, write P ----
  // This wave handles key groups st = ws*2 + {0,1} (32 keys).
#pragma unroll
  for (int stl = 0; stl < 2; ++stl) {
    const int st = ws * 2 + stl;
    if (MASK && (j0 + st * 16 > qrow0 + 15)) {
      // fully-masked key group: zero P, skip the math
#pragma unroll
      for (int r = 0; r < 4; ++r) {
        const int prow = quad * 4 + r;
        const int chunk = (stl * 2 + (nm >> 3)) ^ ((prow ^ (prow >> 2)) & 3);
        pw[(prow * 4 + chunk) * 8 + (nm & 7)] = 0;
      }
      continue;
    }
    const int krow = st * 16 + nm;
    const int r7 = krow & 7;
    bf16x8 kb0 = *(const bf16x8*)&Ksb[(krow * 8 + (quad ^ r7)) * 8];
    bf16x8 kb1 = *(const bf16x8*)&Ksb[(krow * 8 + ((4 + quad) ^ r7)) * 8];
    bf16x8 gb = *(const bf16x8*)&Kspb_[(krow * 2 + (quad & 1)) * 8];
    f32x4 z = {0.f, 0.f, 0.f, 0.f};
    f32x4 s = __builtin_amdgcn_mfma_f32_16x16x32_bf16(qa0, kb0, z, 0, 0, 0);
    s = __builtin_amdgcn_mfma_f32_16x16x32_bf16(qa1, kb1, s, 0, 0, 0);
    f32x4 g = __builtin_amdgcn_mfma_f32_16x16x32_bf16(qspa, gb, z, 0, 0, 0);
#pragma unroll
    for (int r = 0; r < 4; ++r) {
      // sigmoid via raw v_rcp + v_exp (g pre-scaled by log2e)
      float gate = __builtin_amdgcn_rcpf(1.f + __builtin_amdgcn_exp2f(-g[r]));
      float v = s[r] * gate;                   // s pre-scaled by log2e
      if (MASK) {
        const bool edge = (j0 + st * 16 + 15 > qrow0);
        if (edge) {
          const int col = j0 + st * 16 + nm;
          const int rowg = qrow0 + quad * 4 + r;
          v = (col > rowg) ? -INFINITY : v;
        }
      }
      float p = __builtin_amdgcn_exp2f(v);     // exp2(-inf) == 0
      l_r[r] += p;
      const int prow = quad * 4 + r;
      const int chunk = (stl * 2 + (nm >> 3)) ^ ((prow ^ (prow >> 2)) & 3);
      pw[(prow * 4 + chunk) * 8 + (nm & 7)] = f2bf(p);
    }
  }

  // ---- PV (this wave's 32-key half): one k=32 MFMA per d-tile ----
  bf16x8 pa = *(const bf16x8*)&pw[(nm * 4 + (quad ^ ((nm ^ (nm >> 2)) & 3))) * 8];
#pragma unroll
  for (int dt = 0; dt < 4; ++dt) {
    const int vrow = dt * 16 + nm;
    bf16x8 vb = *(const bf16x8*)&Vsb[(vrow * 8 + ((ws * 4 + quad) ^ (vrow & 7))) * 8];
    O[dt] = __builtin_amdgcn_mfma_f32_16x16x32_bf16(pa, vb, O[dt], 0, 0, 0);
  }
}

__global__ __launch_bounds__(512) void attn_kernel(
    const unsigned short* __restrict__ qh, const unsigned short* __restrict__ kh,
    const unsigned short* __restrict__ vt, const unsigned short* __restrict__ qsp,
    const unsigned short* __restrict__ ksp, unsigned short* __restrict__ ao) {
  __shared__ unsigned short Ks[2][64 * 64];
  __shared__ unsigned short Vs[2][64 * 64];
  __shared__ unsigned short Ksp[2][64 * 16];
  __shared__ unsigned short Pw[8][16 * 32];
  __shared__ float Ox[4][16][64];   // [row-group][dt*4+r][lane] exchange
  __shared__ float Lx[4][4][64];

  const int tid = threadIdx.x;
  const int w = tid >> 6;       // 0..7
  const int ws = w >> 2;        // key-half: 0 -> keys 0-31, 1 -> keys 32-63
  const int wr = w & 3;         // q-row group (16 rows)
  const int lane = tid & 63;
  const int nm = lane & 15;
  const int quad = lane >> 4;
  const int bh = blockIdx.y;
  const int b = bh >> 4, h = bh & 15;
  const int hkv = h >> 2;
  const size_t kbase = (size_t)(b * 4 + hkv) * 2048 * 64;
  const size_t vbase = (size_t)(b * 4 + hkv) * 131072;
  const size_t kspb = (size_t)(b * 4 + hkv) * 2048 * 16;

  // staging coords: 512 lanes cover the 64x64 tile in one pass
  const int Lc = tid;
  const int sr = Lc >> 3;
  const int sc = ((Lc & 7) ^ (sr & 7)) * 8;
  unsigned short* pw = &Pw[w][0];

#define STAGE(BUF, J0)                                                         \
  {                                                                            \
    gload16(kh + kbase + (size_t)((J0) + sr) * 64 + sc,                        \
            &Ks[BUF][(w * 64) * 8]);                                           \
    gload16(vt + vbase + (size_t)sr * 2048 + (J0) + sc,                        \
            &Vs[BUF][(w * 64) * 8]);                                           \
    if (w < 2) {                                                               \
      gload16(ksp + kspb + (size_t)((J0) + (Lc >> 1)) * 16 + (Lc & 1) * 8,     \
              &Ksp[BUF][w * 512]);                                             \
    }                                                                          \
  }

  const int qxA = 31 - blockIdx.x;  // heavy tile
  const int qxB = blockIdx.x;       // light tile
  const int qrow0A = qxA * 64 + wr * 16;
  const int qrow0B = qxB * 64 + wr * 16;

  // q fragments for both phases (row group wr; both key-halves use the same Q)
  const size_t qbA = ((size_t)(b * 16 + h) * 2048 + qrow0A + nm) * 64;
  bf16x8 qa0A = *(const bf16x8*)(qh + qbA + quad * 8);
  bf16x8 qa1A = *(const bf16x8*)(qh + qbA + 32 + quad * 8);
  const size_t qbB = ((size_t)(b * 16 + h) * 2048 + qrow0B + nm) * 64;
  bf16x8 qa0B = *(const bf16x8*)(qh + qbB + quad * 8);
  bf16x8 qa1B = *(const bf16x8*)(qh + qbB + 32 + quad * 8);
  bf16x8 qspaA = {0, 0, 0, 0, 0, 0, 0, 0};
  bf16x8 qspaB = {0, 0, 0, 0, 0, 0, 0, 0};
  if (quad < 2) {
    qspaA = *(const bf16x8*)(qsp + ((size_t)(b * 16 + h) * 2048 + qrow0A + nm) * 16 + quad * 8);
    qspaB = *(const bf16x8*)(qsp + ((size_t)(b * 16 + h) * 2048 + qrow0B + nm) * 16 + quad * 8);
  }

  float l_r[4] = {0.f, 0.f, 0.f, 0.f};
  f32x4 O[4] = {{0.f, 0.f, 0.f, 0.f}, {0.f, 0.f, 0.f, 0.f},
                {0.f, 0.f, 0.f, 0.f}, {0.f, 0.f, 0.f, 0.f}};

  // ---------------- phase A (heavy q-tile), pipelined ----------------
  STAGE(0, 0);
  int cur = 0;
  for (int jt = 0; jt < qxA; ++jt) {     // interior tiles: mask-free for all waves
    __syncthreads();   // drains prev STAGE (vmcnt 0) + protects buf reuse
    STAGE(cur ^ 1, (jt + 1) * 64)
    attn_tile<false>(&Ks[cur][0], &Vs[cur][0], &Ksp[cur][0], pw,
                     qa0A, qa1A, qspaA, jt * 64, qrow0A, nm, quad, ws, l_r, O);
    cur ^= 1;
  }
  // diagonal tile jt == qxA (masked) + phase-B tile-0 prefetch
  __syncthreads();
  STAGE(cur ^ 1, 0)
  attn_tile<true>(&Ks[cur][0], &Vs[cur][0], &Ksp[cur][0], pw,
                  qa0A, qa1A, qspaA, qxA * 64, qrow0A, nm, quad, ws, l_r, O);
  cur ^= 1;

  // ---- epilogue A: combine key-halves, store (overlaps B tile-0 DMA) ----
  if (ws == 1) {
#pragma unroll
    for (int dt = 0; dt < 4; ++dt)
#pragma unroll
      for (int r = 0; r < 4; ++r) Ox[wr][dt * 4 + r][lane] = O[dt][r];
#pragma unroll
    for (int r = 0; r < 4; ++r) Lx[wr][r][lane] = l_r[r];
  }
  __syncthreads();
  if (ws == 0) {
#pragma unroll
    for (int r = 0; r < 4; ++r) {
      float v = l_r[r] + Lx[wr][r][lane];
      v += __shfl_xor(v, 1);
      v += __shfl_xor(v, 2);
      v += __shfl_xor(v, 4);
      v += __shfl_xor(v, 8);
      const float inv = __builtin_amdgcn_rcpf(v);
      const int rowg = qrow0A + quad * 4 + r;
      unsigned short* orow = ao + ((size_t)b * 2048 + rowg) * 1024 + h * 64 + nm;
#pragma unroll
      for (int dt = 0; dt < 4; ++dt)
        orow[dt * 16] = f2bf((O[dt][r] + Ox[wr][dt * 4 + r][lane]) * inv);
    }
  }
  // reset accumulators (all waves), AFTER all stores
#pragma unroll
  for (int dt = 0; dt < 4; ++dt) O[dt] = (f32x4){0.f, 0.f, 0.f, 0.f};
#pragma unroll
  for (int r = 0; r < 4; ++r) l_r[r] = 0.f;

  // ---------------- phase B (light q-tile), pipelined ----------------
  for (int jt = 0; jt < qxB; ++jt) {     // interior tiles
    __syncthreads();   // also orders epilogue-A Ox reads vs phase-B writes
    STAGE(cur ^ 1, (jt + 1) * 64)
    attn_tile<false>(&Ks[cur][0], &Vs[cur][0], &Ksp[cur][0], pw,
                     qa0B, qa1B, qspaB, jt * 64, qrow0B, nm, quad, ws, l_r, O);
    cur ^= 1;
  }
  // diagonal tile jt == qxB (masked), no prefetch
  __syncthreads();
  attn_tile<true>(&Ks[cur][0], &Vs[cur][0], &Ksp[cur][0], pw,
                  qa0B, qa1B, qspaB, qxB * 64, qrow0B, nm, quad, ws, l_r, O);

  // ---- epilogue B ----
  if (ws == 1) {
#pragma unroll
    for (int dt = 0; dt < 4; ++dt)
#pragma unroll
      for (int r = 0; r < 4; ++r) Ox[wr][dt * 4 + r][lane] = O[dt][r];
#pragma unroll
    for (int r = 0; r < 4; ++r) Lx[wr][r][lane] = l_r[r];
  }
  __syncthreads();
  if (ws == 0) {
#pragma unroll
    for (int r = 0; r < 4; ++r) {
      float v = l_r[r] + Lx[wr][r][lane];
      v += __shfl_xor(v, 1);
      v += __shfl_xor(v, 2);
      v += __shfl_xor(v, 4);
      v += __shfl_xor(v, 8);
      const float inv = __builtin_amdgcn_rcpf(v);
      const int rowg = qrow0B + quad * 4 + r;
      unsigned short* orow = ao + ((size_t)b * 2048 + rowg) * 1024 + h * 64 + nm;
#pragma unroll
      for (int dt = 0; dt < 4; ++dt)
        orow[dt * 16] = f2bf((O[dt][r] + Ox[wr][dt * 4 + r][lane]) * inv);
    }
  }
#undef STAGE
}

// ---------------------------------------------------------------------------
extern "C" void kernel_launch(void* const* d_in, const int* in_sizes, int n_in,
                              void* d_out, int out_size, void* d_ws,
                              size_t ws_size, hipStream_t stream) {
  const float* x = (const float*)d_in[0];
  const float* Wq = (const float*)d_in[1];
  const float* Wk = (const float*)d_in[2];
  const float* Wv = (const float*)d_in[3];
  const float* Wo = (const float*)d_in[4];
  const float* bo = (const float*)d_in[5];
  const float* Ws = (const float*)d_in[6];
  const float* bs = (const float*)d_in[7];
  float* out = (float*)d_out;

  // Workspace layout (bytes):
  char* wsb = (char*)d_ws;
  float* proj = (float*)wsb;                                  // 25,165,824 B (dead after rope/vt)
  unsigned short* aob  = (unsigned short*)wsb;                // 8,388,608 B (alias proj head)
  unsigned short* qh   = (unsigned short*)(wsb + 25165824);   // 8,388,608 B
  unsigned short* kh   = (unsigned short*)(wsb + 33554432);   // 2,097,152 B
  unsigned short* vtb  = (unsigned short*)(wsb + 35651584);   // 2,097,152 B
  unsigned short* qsp  = (unsigned short*)(wsb + 37748736);   // 2,097,152 B
  unsigned short* ksp  = (unsigned short*)(wsb + 39845888);   //   524,288 B
  unsigned short* xb   = (unsigned short*)(wsb + 40370176);   // 8,388,608 B
  unsigned short* wqkv = (unsigned short*)(wsb + 48758784);   // 3,145,728 B
  unsigned short* wob  = (unsigned short*)(wsb + 51904512);   // 2,097,152 B

  convert_bf16<<<dim3(3328), 256, 0, stream>>>(x, Wq, Wk, Wv, Wo, xb, wqkv, wob);
  gemm_bf16<<<dim3(12, 64), 256, 0, stream>>>(xb, wqkv, nullptr, proj, 1536);
  rope_scatter<<<dim3(4096), 256, 0, stream>>>(proj, Ws, bs, qh, kh, qsp, ksp);
  v_transpose<<<dim3(32, 8), 256, 0, stream>>>(proj, vtb);
  attn_kernel<<<dim3(16, 32), 512, 0, stream>>>(qh, kh, vtb, qsp, ksp, aob);
  gemm_bf16_128<<<dim3(8, 32), 256, 0, stream>>>(aob, wob, bo, out, 1024);
}

// Round 13
// 184.192 us; speedup vs baseline: 1.5315x; 1.0566x over previous
//
#include <hip/hip_runtime.h>
#include <math.h>

// Problem constants
#define B_ 2
#define S_ 2048
#define D_ 1024
#define H_ 16
#define HKV_ 4
#define HD_ 64
#define SD_ 16

typedef __attribute__((ext_vector_type(8))) short bf16x8;
typedef __attribute__((ext_vector_type(4))) float f32x4;
typedef __attribute__((ext_vector_type(8))) unsigned short us8;
typedef __attribute__((ext_vector_type(4))) unsigned short us4;

#define LOG2E 1.4426950408889634f

__device__ __forceinline__ unsigned short f2bf(float f) {
  unsigned int u = __builtin_bit_cast(unsigned int, f);
  u += 0x7fffu + ((u >> 16) & 1u);   // RNE; inputs are finite
  return (unsigned short)(u >> 16);
}

__device__ __forceinline__ float bf2f(unsigned short u) {
  unsigned int x = ((unsigned int)u) << 16;
  return __builtin_bit_cast(float, x);
}

// global -> LDS async DMA, 16B per lane; LDS dest wave-uniform base + lane*16.
__device__ __forceinline__ void gload16(const unsigned short* g, unsigned short* l) {
  __builtin_amdgcn_global_load_lds(
      (const __attribute__((address_space(1))) unsigned int*)g,
      (__attribute__((address_space(3))) unsigned int*)l, 16, 0, 0);
}

// ---------------------------------------------------------------------------
// Kernel 0: fp32 -> bf16 convert for GEMM operands.
// ---------------------------------------------------------------------------
__global__ __launch_bounds__(256) void convert_bf16(
    const float* __restrict__ x, const float* __restrict__ wq,
    const float* __restrict__ wk, const float* __restrict__ wv,
    const float* __restrict__ wo, unsigned short* __restrict__ xb,
    unsigned short* __restrict__ wqkv, unsigned short* __restrict__ wob) {
  const int blk = blockIdx.x;
  const float* src;
  unsigned short* dst;
  int off;
  if (blk < 2048)      { src = x;  dst = xb;             off = blk * 2048; }
  else if (blk < 2560) { src = wq; dst = wqkv;           off = (blk - 2048) * 2048; }
  else if (blk < 2688) { src = wk; dst = wqkv + 1048576; off = (blk - 2560) * 2048; }
  else if (blk < 2816) { src = wv; dst = wqkv + 1310720; off = (blk - 2688) * 2048; }
  else                 { src = wo; dst = wob;            off = (blk - 2816) * 2048; }
  const int i = off + threadIdx.x * 8;
  float4 a = *(const float4*)(src + i);
  float4 b = *(const float4*)(src + i + 4);
  us8 o;
  o[0] = f2bf(a.x); o[1] = f2bf(a.y); o[2] = f2bf(a.z); o[3] = f2bf(a.w);
  o[4] = f2bf(b.x); o[5] = f2bf(b.y); o[6] = f2bf(b.z); o[7] = f2bf(b.w);
  *(us8*)(dst + i) = o;
}

// ---------------------------------------------------------------------------
// Kernel A: bf16 MFMA GEMM, 64x128 tile, bf16 OUTPUT (no bias) — gemm1 only.
// R24: proj is now bf16 (downstream consumers round to bf16 anyway) ->
// gemm1 write traffic 25.2 -> 12.6 MB, rope/vt reads halve (~27 MB HBM
// saved). Grid (12,64)=768 blocks = 3.0 balanced rounds (proven config).
// ---------------------------------------------------------------------------
__global__ __launch_bounds__(256) void gemm_bf16_p(
    const unsigned short* __restrict__ A, const unsigned short* __restrict__ Bm,
    unsigned short* __restrict__ C, int N) {
  __shared__ unsigned short As[64 * 64];
  __shared__ unsigned short Bs[128 * 64];
  const int tid = threadIdx.x;
  const int w = tid >> 6, lane = tid & 63;
  const int nm = lane & 15, quad = lane >> 4;
  const int m0 = blockIdx.y * 64, n0 = blockIdx.x * 128;
  const int wn = w * 32;

  f32x4 acc[4][2] = {};
  int arow[2], acol[2], brow[4], bcol[4];
#pragma unroll
  for (int it = 0; it < 2; ++it) {
    int s = it * 256 + tid;
    arow[it] = s >> 3;
    acol[it] = ((s & 7) ^ (arow[it] & 7)) * 8;
  }
#pragma unroll
  for (int it = 0; it < 4; ++it) {
    int s = it * 256 + tid;
    brow[it] = s >> 3;
    bcol[it] = ((s & 7) ^ (brow[it] & 7)) * 8;
  }

  for (int k0 = 0; k0 < 1024; k0 += 64) {
    __syncthreads();
#pragma unroll
    for (int it = 0; it < 2; ++it)
      gload16(A + (size_t)(m0 + arow[it]) * 1024 + k0 + acol[it],
              &As[(it * 256 + w * 64) * 8]);
#pragma unroll
    for (int it = 0; it < 4; ++it)
      gload16(Bm + (size_t)(n0 + brow[it]) * 1024 + k0 + bcol[it],
              &Bs[(it * 256 + w * 64) * 8]);
    __syncthreads();

#pragma unroll
    for (int ks = 0; ks < 2; ++ks) {
      const int cq = ks * 4 + quad;
      bf16x8 af[4], bfr[2];
#pragma unroll
      for (int mi = 0; mi < 4; ++mi) {
        const int m = mi * 16 + nm;
        af[mi] = *(const bf16x8*)&As[(m * 8 + (cq ^ (m & 7))) * 8];
      }
#pragma unroll
      for (int ni = 0; ni < 2; ++ni) {
        const int n = wn + ni * 16 + nm;
        bfr[ni] = *(const bf16x8*)&Bs[(n * 8 + (cq ^ (n & 7))) * 8];
      }
#pragma unroll
      for (int mi = 0; mi < 4; ++mi)
#pragma unroll
        for (int ni = 0; ni < 2; ++ni)
          acc[mi][ni] = __builtin_amdgcn_mfma_f32_16x16x32_bf16(
              af[mi], bfr[ni], acc[mi][ni], 0, 0, 0);
    }
  }

#pragma unroll
  for (int mi = 0; mi < 4; ++mi) {
#pragma unroll
    for (int r = 0; r < 4; ++r) {
      const int row = m0 + mi * 16 + quad * 4 + r;
      unsigned short* crow = C + (size_t)row * N + n0 + wn + nm;
#pragma unroll
      for (int ni = 0; ni < 2; ++ni) crow[ni * 16] = f2bf(acc[mi][ni][r]);
    }
  }
}

// ---------------------------------------------------------------------------
// Kernel D: bf16 MFMA GEMM, 64x128 tile, f32 output + bias — gemm2.
// R24: reverted from 128^2 (R23 algebra: g2_128 = g2_64 + 8.1 us — grid
// (8,32)=1 block/CU = 1 wave/SIMD, no latency cover). Grid (8,64)=512
// blocks = 2 blocks/CU, proven R17 config.
// ---------------------------------------------------------------------------
__global__ __launch_bounds__(256) void gemm_bf16(
    const unsigned short* __restrict__ A, const unsigned short* __restrict__ Bm,
    const float* __restrict__ bias, float* __restrict__ C, int N) {
  __shared__ unsigned short As[64 * 64];
  __shared__ unsigned short Bs[128 * 64];
  const int tid = threadIdx.x;
  const int w = tid >> 6, lane = tid & 63;
  const int nm = lane & 15, quad = lane >> 4;
  const int m0 = blockIdx.y * 64, n0 = blockIdx.x * 128;
  const int wn = w * 32;

  f32x4 acc[4][2] = {};
  int arow[2], acol[2], brow[4], bcol[4];
#pragma unroll
  for (int it = 0; it < 2; ++it) {
    int s = it * 256 + tid;
    arow[it] = s >> 3;
    acol[it] = ((s & 7) ^ (arow[it] & 7)) * 8;
  }
#pragma unroll
  for (int it = 0; it < 4; ++it) {
    int s = it * 256 + tid;
    brow[it] = s >> 3;
    bcol[it] = ((s & 7) ^ (brow[it] & 7)) * 8;
  }

  for (int k0 = 0; k0 < 1024; k0 += 64) {
    __syncthreads();
#pragma unroll
    for (int it = 0; it < 2; ++it)
      gload16(A + (size_t)(m0 + arow[it]) * 1024 + k0 + acol[it],
              &As[(it * 256 + w * 64) * 8]);
#pragma unroll
    for (int it = 0; it < 4; ++it)
      gload16(Bm + (size_t)(n0 + brow[it]) * 1024 + k0 + bcol[it],
              &Bs[(it * 256 + w * 64) * 8]);
    __syncthreads();

#pragma unroll
    for (int ks = 0; ks < 2; ++ks) {
      const int cq = ks * 4 + quad;
      bf16x8 af[4], bfr[2];
#pragma unroll
      for (int mi = 0; mi < 4; ++mi) {
        const int m = mi * 16 + nm;
        af[mi] = *(const bf16x8*)&As[(m * 8 + (cq ^ (m & 7))) * 8];
      }
#pragma unroll
      for (int ni = 0; ni < 2; ++ni) {
        const int n = wn + ni * 16 + nm;
        bfr[ni] = *(const bf16x8*)&Bs[(n * 8 + (cq ^ (n & 7))) * 8];
      }
#pragma unroll
      for (int mi = 0; mi < 4; ++mi)
#pragma unroll
        for (int ni = 0; ni < 2; ++ni)
          acc[mi][ni] = __builtin_amdgcn_mfma_f32_16x16x32_bf16(
              af[mi], bfr[ni], acc[mi][ni], 0, 0, 0);
    }
  }

  float bv[2] = {0.f, 0.f};
  if (bias) {
#pragma unroll
    for (int ni = 0; ni < 2; ++ni) bv[ni] = bias[n0 + wn + ni * 16 + nm];
  }
#pragma unroll
  for (int mi = 0; mi < 4; ++mi) {
#pragma unroll
    for (int r = 0; r < 4; ++r) {
      const int row = m0 + mi * 16 + quad * 4 + r;
      float* crow = C + (size_t)row * N + n0 + wn + nm;
#pragma unroll
      for (int ni = 0; ni < 2; ++ni) crow[ni * 16] = acc[mi][ni][r] + bv[ni];
    }
  }
}

// ---------------------------------------------------------------------------
// Kernel B (fused): blocks 0..4095 = RoPE + scatter + sp-proj (bf16 proj in);
// blocks 4096..4351 = V transpose (bf16 proj in). Both depend only on proj;
// fusing saves a launch and overlaps vt under rope's tail.
// ---------------------------------------------------------------------------
__global__ __launch_bounds__(256) void rope_vt(
    const unsigned short* __restrict__ P, const float* __restrict__ Ws,
    const float* __restrict__ bs, unsigned short* __restrict__ qh,
    unsigned short* __restrict__ kh, unsigned short* __restrict__ qsp,
    unsigned short* __restrict__ ksp, unsigned short* __restrict__ vt) {
  __shared__ float wsl[16 * 64];
  __shared__ float bsl[16];
  __shared__ float rbuf[4][64];
  __shared__ unsigned short t_[64 * 72];
  const int tid = threadIdx.x;

  if (blockIdx.x >= 4096) {
    // ---- V transpose part ----
    const int t = blockIdx.x - 4096;
    const int bkv = t >> 5;
    const int s0 = (t & 31) * 64;
    const int b = bkv >> 2, hkv = bkv & 3;
    const int sl = tid >> 2;
    const int c0 = (tid & 3) * 16;
    const unsigned short* src =
        P + ((size_t)b * 2048 + s0 + sl) * 1536 + 1280 + hkv * 64 + c0;
    us8 o0 = *(const us8*)(src);
    us8 o1 = *(const us8*)(src + 8);
    *(us8*)&t_[sl * 72 + c0] = o0;
    *(us8*)&t_[sl * 72 + c0 + 8] = o1;
    __syncthreads();
    const int d = tid >> 2;
    const int sc_ = (tid & 3) * 16;
    us8 w0, w1;
#pragma unroll
    for (int k = 0; k < 8; ++k) w0[k] = t_[(sc_ + k) * 72 + d];
#pragma unroll
    for (int k = 0; k < 8; ++k) w1[k] = t_[(sc_ + 8 + k) * 72 + d];
    unsigned short* dst = vt + (size_t)bkv * 131072 + (size_t)d * 2048 + s0 + sc_;
    *(us8*)dst = w0;
    *(us8*)(dst + 8) = w1;
    return;
  }

  // ---- RoPE part ----
  const int row = blockIdx.x;
  const int b = row >> 11;
  const int s = row & 2047;
  {
    *(float4*)&wsl[tid * 4] = *(const float4*)&Ws[tid * 4];
    if (tid < 16) bsl[tid] = bs[tid];
  }
  __syncthreads();
  const int w = tid >> 6, lane = tid & 63;
  const int i = lane & 31, halfu = lane >> 5;
  const float theta = powf(10000.f, -((float)(2 * i) * (1.f / 64.f)));
  const float f = (float)s * theta;
  const float cf = cosf(f);
  const float sf = sinf(f);
  for (int slot = w; slot < 20; slot += 4) {
    float val = bf2f(P[(size_t)row * 1536 + slot * 64 + lane]);
    float partner = __shfl_xor(val, 32);
    float rot = halfu ? partner : -partner;
    float r = val * cf + rot * sf;
    unsigned short* dst;
    unsigned short* spdst;
    float qscale, spscale;
    if (slot < 16) {
      dst = qh + ((size_t)(b * 16 + slot) * 2048 + s) * 64;
      spdst = qsp + ((size_t)(b * 16 + slot) * 2048 + s) * 16;
      qscale = 0.125f * LOG2E; spscale = 0.25f * LOG2E;
    } else {
      int hh = slot - 16;
      dst = kh + ((size_t)(b * 4 + hh) * 2048 + s) * 64;
      spdst = ksp + ((size_t)(b * 4 + hh) * 2048 + s) * 16;
      qscale = 1.f; spscale = 1.f;
    }
    dst[lane] = f2bf(r * qscale);
    rbuf[w][lane] = r;
    int p = lane >> 4, j = lane & 15;
    float partial = 0.f;
#pragma unroll
    for (int t2 = 0; t2 < 16; ++t2)
      partial += wsl[j * 64 + p * 16 + t2] * rbuf[w][p * 16 + t2];
    partial += __shfl_xor(partial, 16);
    partial += __shfl_xor(partial, 32);
    if (p == 0) spdst[j] = f2bf((partial + bsl[j]) * spscale);
  }
}

// ---------------------------------------------------------------------------
// Kernel C: gated causal flash attention. Verbatim R17 (proven 57 us):
// 8-wave key-split, 2-phase pipeline, mask peel.
// ---------------------------------------------------------------------------
template <bool MASK>
__device__ __forceinline__ void attn_tile(
    const unsigned short* __restrict__ Ksb, const unsigned short* __restrict__ Vsb,
    const unsigned short* __restrict__ Kspb_, unsigned short* __restrict__ pw,
    bf16x8 qa0, bf16x8 qa1, bf16x8 qspa, int j0, int qrow0, int nm, int quad,
    int ws, float l_r[4], f32x4 O[4]) {
  // ---- QK^T + gate -> p = exp2(s'*gate), accumulate l, write P ----
  // This wave handles key groups st = ws*2 + {0,1} (32 keys).
#pragma unroll
  for (int stl = 0; stl < 2; ++stl) {
    const int st = ws * 2 + stl;
    if (MASK && (j0 + st * 16 > qrow0 + 15)) {
      // fully-masked key group: zero P, skip the math
#pragma unroll
      for (int r = 0; r < 4; ++r) {
        const int prow = quad * 4 + r;
        const int chunk = (stl * 2 + (nm >> 3)) ^ ((prow ^ (prow >> 2)) & 3);
        pw[(prow * 4 + chunk) * 8 + (nm & 7)] = 0;
      }
      continue;
    }
    const int krow = st * 16 + nm;
    const int r7 = krow & 7;
    bf16x8 kb0 = *(const bf16x8*)&Ksb[(krow * 8 + (quad ^ r7)) * 8];
    bf16x8 kb1 = *(const bf16x8*)&Ksb[(krow * 8 + ((4 + quad) ^ r7)) * 8];
    bf16x8 gb = *(const bf16x8*)&Kspb_[(krow * 2 + (quad & 1)) * 8];
    f32x4 z = {0.f, 0.f, 0.f, 0.f};
    f32x4 s = __builtin_amdgcn_mfma_f32_16x16x32_bf16(qa0, kb0, z, 0, 0, 0);
    s = __builtin_amdgcn_mfma_f32_16x16x32_bf16(qa1, kb1, s, 0, 0, 0);
    f32x4 g = __builtin_amdgcn_mfma_f32_16x16x32_bf16(qspa, gb, z, 0, 0, 0);
#pragma unroll
    for (int r = 0; r < 4; ++r) {
      // sigmoid via raw v_rcp + v_exp (g pre-scaled by log2e)
      float gate = __builtin_amdgcn_rcpf(1.f + __builtin_amdgcn_exp2f(-g[r]));
      float v = s[r] * gate;                   // s pre-scaled by log2e
      if (MASK) {
        const bool edge = (j0 + st * 16 + 15 > qrow0);
        if (edge) {
          const int col = j0 + st * 16 + nm;
          const int rowg = qrow0 + quad * 4 + r;
          v = (col > rowg) ? -INFINITY : v;
        }
      }
      float p = __builtin_amdgcn_exp2f(v);     // exp2(-inf) == 0
      l_r[r] += p;
      const int prow = quad * 4 + r;
      const int chunk = (stl * 2 + (nm >> 3)) ^ ((prow ^ (prow >> 2)) & 3);
      pw[(prow * 4 + chunk) * 8 + (nm & 7)] = f2bf(p);
    }
  }

  // ---- PV (this wave's 32-key half): one k=32 MFMA per d-tile ----
  bf16x8 pa = *(const bf16x8*)&pw[(nm * 4 + (quad ^ ((nm ^ (nm >> 2)) & 3))) * 8];
#pragma unroll
  for (int dt = 0; dt < 4; ++dt) {
    const int vrow = dt * 16 + nm;
    bf16x8 vb = *(const bf16x8*)&Vsb[(vrow * 8 + ((ws * 4 + quad) ^ (vrow & 7))) * 8];
    O[dt] = __builtin_amdgcn_mfma_f32_16x16x32_bf16(pa, vb, O[dt], 0, 0, 0);
  }
}

__global__ __launch_bounds__(512) void attn_kernel(
    const unsigned short* __restrict__ qh, const unsigned short* __restrict__ kh,
    const unsigned short* __restrict__ vt, const unsigned short* __restrict__ qsp,
    const unsigned short* __restrict__ ksp, unsigned short* __restrict__ ao) {
  __shared__ unsigned short Ks[2][64 * 64];
  __shared__ unsigned short Vs[2][64 * 64];
  __shared__ unsigned short Ksp[2][64 * 16];
  __shared__ unsigned short Pw[8][16 * 32];
  __shared__ float Ox[4][16][64];   // [row-group][dt*4+r][lane] exchange
  __shared__ float Lx[4][4][64];

  const int tid = threadIdx.x;
  const int w = tid >> 6;       // 0..7
  const int ws = w >> 2;        // key-half: 0 -> keys 0-31, 1 -> keys 32-63
  const int wr = w & 3;         // q-row group (16 rows)
  const int lane = tid & 63;
  const int nm = lane & 15;
  const int quad = lane >> 4;
  const int bh = blockIdx.y;
  const int b = bh >> 4, h = bh & 15;
  const int hkv = h >> 2;
  const size_t kbase = (size_t)(b * 4 + hkv) * 2048 * 64;
  const size_t vbase = (size_t)(b * 4 + hkv) * 131072;
  const size_t kspb = (size_t)(b * 4 + hkv) * 2048 * 16;

  // staging coords: 512 lanes cover the 64x64 tile in one pass
  const int Lc = tid;
  const int sr = Lc >> 3;
  const int sc = ((Lc & 7) ^ (sr & 7)) * 8;
  unsigned short* pw = &Pw[w][0];

#define STAGE(BUF, J0)                                                         \
  {                                                                            \
    gload16(kh + kbase + (size_t)((J0) + sr) * 64 + sc,                        \
            &Ks[BUF][(w * 64) * 8]);                                           \
    gload16(vt + vbase + (size_t)sr * 2048 + (J0) + sc,                        \
            &Vs[BUF][(w * 64) * 8]);                                           \
    if (w < 2) {                                                               \
      gload16(ksp + kspb + (size_t)((J0) + (Lc >> 1)) * 16 + (Lc & 1) * 8,     \
              &Ksp[BUF][w * 512]);                                             \
    }                                                                          \
  }

  const int qxA = 31 - blockIdx.x;  // heavy tile
  const int qxB = blockIdx.x;       // light tile
  const int qrow0A = qxA * 64 + wr * 16;
  const int qrow0B = qxB * 64 + wr * 16;

  // q fragments for both phases (row group wr; both key-halves use the same Q)
  const size_t qbA = ((size_t)(b * 16 + h) * 2048 + qrow0A + nm) * 64;
  bf16x8 qa0A = *(const bf16x8*)(qh + qbA + quad * 8);
  bf16x8 qa1A = *(const bf16x8*)(qh + qbA + 32 + quad * 8);
  const size_t qbB = ((size_t)(b * 16 + h) * 2048 + qrow0B + nm) * 64;
  bf16x8 qa0B = *(const bf16x8*)(qh + qbB + quad * 8);
  bf16x8 qa1B = *(const bf16x8*)(qh + qbB + 32 + quad * 8);
  bf16x8 qspaA = {0, 0, 0, 0, 0, 0, 0, 0};
  bf16x8 qspaB = {0, 0, 0, 0, 0, 0, 0, 0};
  if (quad < 2) {
    qspaA = *(const bf16x8*)(qsp + ((size_t)(b * 16 + h) * 2048 + qrow0A + nm) * 16 + quad * 8);
    qspaB = *(const bf16x8*)(qsp + ((size_t)(b * 16 + h) * 2048 + qrow0B + nm) * 16 + quad * 8);
  }

  float l_r[4] = {0.f, 0.f, 0.f, 0.f};
  f32x4 O[4] = {{0.f, 0.f, 0.f, 0.f}, {0.f, 0.f, 0.f, 0.f},
                {0.f, 0.f, 0.f, 0.f}, {0.f, 0.f, 0.f, 0.f}};

  // ---------------- phase A (heavy q-tile), pipelined ----------------
  STAGE(0, 0);
  int cur = 0;
  for (int jt = 0; jt < qxA; ++jt) {     // interior tiles: mask-free for all waves
    __syncthreads();   // drains prev STAGE (vmcnt 0) + protects buf reuse
    STAGE(cur ^ 1, (jt + 1) * 64)
    attn_tile<false>(&Ks[cur][0], &Vs[cur][0], &Ksp[cur][0], pw,
                     qa0A, qa1A, qspaA, jt * 64, qrow0A, nm, quad, ws, l_r, O);
    cur ^= 1;
  }
  // diagonal tile jt == qxA (masked) + phase-B tile-0 prefetch
  __syncthreads();
  STAGE(cur ^ 1, 0)
  attn_tile<true>(&Ks[cur][0], &Vs[cur][0], &Ksp[cur][0], pw,
                  qa0A, qa1A, qspaA, qxA * 64, qrow0A, nm, quad, ws, l_r, O);
  cur ^= 1;

  // ---- epilogue A: combine key-halves, store (overlaps B tile-0 DMA) ----
  if (ws == 1) {
#pragma unroll
    for (int dt = 0; dt < 4; ++dt)
#pragma unroll
      for (int r = 0; r < 4; ++r) Ox[wr][dt * 4 + r][lane] = O[dt][r];
#pragma unroll
    for (int r = 0; r < 4; ++r) Lx[wr][r][lane] = l_r[r];
  }
  __syncthreads();
  if (ws == 0) {
#pragma unroll
    for (int r = 0; r < 4; ++r) {
      float v = l_r[r] + Lx[wr][r][lane];
      v += __shfl_xor(v, 1);
      v += __shfl_xor(v, 2);
      v += __shfl_xor(v, 4);
      v += __shfl_xor(v, 8);
      const float inv = __builtin_amdgcn_rcpf(v);
      const int rowg = qrow0A + quad * 4 + r;
      unsigned short* orow = ao + ((size_t)b * 2048 + rowg) * 1024 + h * 64 + nm;
#pragma unroll
      for (int dt = 0; dt < 4; ++dt)
        orow[dt * 16] = f2bf((O[dt][r] + Ox[wr][dt * 4 + r][lane]) * inv);
    }
  }
  // reset accumulators (all waves), AFTER all stores
#pragma unroll
  for (int dt = 0; dt < 4; ++dt) O[dt] = (f32x4){0.f, 0.f, 0.f, 0.f};
#pragma unroll
  for (int r = 0; r < 4; ++r) l_r[r] = 0.f;

  // ---------------- phase B (light q-tile), pipelined ----------------
  for (int jt = 0; jt < qxB; ++jt) {     // interior tiles
    __syncthreads();   // also orders epilogue-A Ox reads vs phase-B writes
    STAGE(cur ^ 1, (jt + 1) * 64)
    attn_tile<false>(&Ks[cur][0], &Vs[cur][0], &Ksp[cur][0], pw,
                     qa0B, qa1B, qspaB, jt * 64, qrow0B, nm, quad, ws, l_r, O);
    cur ^= 1;
  }
  // diagonal tile jt == qxB (masked), no prefetch
  __syncthreads();
  attn_tile<true>(&Ks[cur][0], &Vs[cur][0], &Ksp[cur][0], pw,
                  qa0B, qa1B, qspaB, qxB * 64, qrow0B, nm, quad, ws, l_r, O);

  // ---- epilogue B ----
  if (ws == 1) {
#pragma unroll
    for (int dt = 0; dt < 4; ++dt)
#pragma unroll
      for (int r = 0; r < 4; ++r) Ox[wr][dt * 4 + r][lane] = O[dt][r];
#pragma unroll
    for (int r = 0; r < 4; ++r) Lx[wr][r][lane] = l_r[r];
  }
  __syncthreads();
  if (ws == 0) {
#pragma unroll
    for (int r = 0; r < 4; ++r) {
      float v = l_r[r] + Lx[wr][r][lane];
      v += __shfl_xor(v, 1);
      v += __shfl_xor(v, 2);
      v += __shfl_xor(v, 4);
      v += __shfl_xor(v, 8);
      const float inv = __builtin_amdgcn_rcpf(v);
      const int rowg = qrow0B + quad * 4 + r;
      unsigned short* orow = ao + ((size_t)b * 2048 + rowg) * 1024 + h * 64 + nm;
#pragma unroll
      for (int dt = 0; dt < 4; ++dt)
        orow[dt * 16] = f2bf((O[dt][r] + Ox[wr][dt * 4 + r][lane]) * inv);
    }
  }
#undef STAGE
}

// ---------------------------------------------------------------------------
extern "C" void kernel_launch(void* const* d_in, const int* in_sizes, int n_in,
                              void* d_out, int out_size, void* d_ws,
                              size_t ws_size, hipStream_t stream) {
  const float* x = (const float*)d_in[0];
  const float* Wq = (const float*)d_in[1];
  const float* Wk = (const float*)d_in[2];
  const float* Wv = (const float*)d_in[3];
  const float* Wo = (const float*)d_in[4];
  const float* bo = (const float*)d_in[5];
  const float* Ws = (const float*)d_in[6];
  const float* bs = (const float*)d_in[7];
  float* out = (float*)d_out;

  // Workspace layout (bytes):
  char* wsb = (char*)d_ws;
  unsigned short* projb = (unsigned short*)wsb;               // 12,582,912 B (bf16; dead after rope_vt)
  unsigned short* aob  = (unsigned short*)wsb;                // 8,388,608 B (alias projb head)
  unsigned short* qh   = (unsigned short*)(wsb + 25165824);   // 8,388,608 B
  unsigned short* kh   = (unsigned short*)(wsb + 33554432);   // 2,097,152 B
  unsigned short* vtb  = (unsigned short*)(wsb + 35651584);   // 2,097,152 B
  unsigned short* qsp  = (unsigned short*)(wsb + 37748736);   // 2,097,152 B
  unsigned short* ksp  = (unsigned short*)(wsb + 39845888);   //   524,288 B
  unsigned short* xb   = (unsigned short*)(wsb + 40370176);   // 8,388,608 B
  unsigned short* wqkv = (unsigned short*)(wsb + 48758784);   // 3,145,728 B
  unsigned short* wob  = (unsigned short*)(wsb + 51904512);   // 2,097,152 B

  convert_bf16<<<dim3(3328), 256, 0, stream>>>(x, Wq, Wk, Wv, Wo, xb, wqkv, wob);
  gemm_bf16_p<<<dim3(12, 64), 256, 0, stream>>>(xb, wqkv, projb, 1536);
  rope_vt<<<dim3(4352), 256, 0, stream>>>(projb, Ws, bs, qh, kh, qsp, ksp, vtb);
  attn_kernel<<<dim3(16, 32), 512, 0, stream>>>(qh, kh, vtb, qsp, ksp, aob);
  gemm_bf16<<<dim3(8, 64), 256, 0, stream>>>(aob, wob, bo, out, 1024);
}